// Round 1
// baseline (1868.890 us; speedup 1.0000x reference)
//
#include <hip/hip_runtime.h>

#define N_PTS 100000
#define K 16
#define CIN 64
#define CMID 32
#define PEH 32
#define PEO 32
#define WNH 8
#define WNO 16
#define CONC 64          // CMID + PEO
#define LINI 1024        // CONC * WNO
#define LINO 64
#define COUT 128
#define P 8              // points per block
#define AROW 1032        // padded a_flat row stride in floats (1032 % 32 == 8)

__device__ __forceinline__ float lrelu(float x) { return x > 0.f ? x : 0.1f * x; }

// Kernel 1: feats = dense_feats @ u1_w + u1_b   (N x 32)
__global__ __launch_bounds__(256) void u1_kernel(const float* __restrict__ df,
                                                 const float* __restrict__ w,
                                                 const float* __restrict__ b,
                                                 float* __restrict__ feats) {
    int t = blockIdx.x * 256 + threadIdx.x;
    int n = t >> 3, g = t & 7;      // 8 threads per row, 4 outputs each
    if (n >= N_PTS) return;
    int c = g * 4;
    float4 acc = *(const float4*)(b + c);
    const float* row = df + (size_t)n * CIN;
    #pragma unroll
    for (int j = 0; j < CIN; j += 4) {
        float4 f = *(const float4*)(row + j);
        float4 w0 = *(const float4*)(w + (j + 0) * CMID + c);
        float4 w1 = *(const float4*)(w + (j + 1) * CMID + c);
        float4 w2 = *(const float4*)(w + (j + 2) * CMID + c);
        float4 w3 = *(const float4*)(w + (j + 3) * CMID + c);
        acc.x += f.x * w0.x + f.y * w1.x + f.z * w2.x + f.w * w3.x;
        acc.y += f.x * w0.y + f.y * w1.y + f.z * w2.y + f.w * w3.y;
        acc.z += f.x * w0.z + f.y * w1.z + f.z * w2.z + f.w * w3.z;
        acc.w += f.x * w0.w + f.y * w1.w + f.z * w2.w + f.w * w3.w;
    }
    *(float4*)(feats + (size_t)n * CMID + c) = acc;
}

// Main fused kernel: per block of 256 threads handles P=8 points.
__global__ __launch_bounds__(256) void pc_main_kernel(
    const float* __restrict__ xyz, const float* __restrict__ df,
    const int* __restrict__ nei,
    const float* __restrict__ pe_w1, const float* __restrict__ pe_b1,
    const float* __restrict__ pe_w2, const float* __restrict__ pe_b2,
    const float* __restrict__ wn_w1, const float* __restrict__ wn_b1,
    const float* __restrict__ wn_w2, const float* __restrict__ wn_b2,
    const float* __restrict__ wn_w3, const float* __restrict__ wn_b3,
    const float* __restrict__ lin_w, const float* __restrict__ lin_b,
    const float* __restrict__ u2_w, const float* __restrict__ u2_b,
    const float* __restrict__ sc_w, const float* __restrict__ sc_b,
    const float* __restrict__ feats, float* __restrict__ out)
{
    __shared__ __align__(16) float a_flat[P][AROW];     // 33,024 B
    __shared__ __align__(16) float xbuf[P][LINO];       //  2,048 B
    __shared__ __align__(16) float nf[4][K * CONC];     // 16,384 B (per-wave new_feat)
    __shared__ __align__(16) float loc_s[4][K * 3];     //    768 B
    __shared__ __align__(16) float wnw_s[4][K * WNO];   //  4,096 B
    __shared__ __align__(16) float ph_s[4][K * PEH];    //  8,192 B
    // total ~64.5 KB -> 2 blocks/CU

    const int tid = threadIdx.x;
    const int wv = tid >> 6;
    const int lane = tid & 63;
    const int pb = blockIdx.x * P;

    for (int it = 0; it < 2; ++it) {
        const int p = wv * 2 + it;
        const int pt = pb + p;

        // ---- Stage A: localized coords + gather feats ----
        if (lane < K) {
            int k = lane;
            int idx = nei[pt * K + k];
            float cx = xyz[pt * 3 + 0], cy = xyz[pt * 3 + 1], cz = xyz[pt * 3 + 2];
            float lx = xyz[idx * 3 + 0] - cx;
            float ly = xyz[idx * 3 + 1] - cy;
            float lz = xyz[idx * 3 + 2] - cz;
            loc_s[wv][k * 3 + 0] = lx;
            loc_s[wv][k * 3 + 1] = ly;
            loc_s[wv][k * 3 + 2] = lz;
            float* lo = out + (size_t)N_PTS * COUT + (size_t)(pt * K + k) * 3;
            lo[0] = lx; lo[1] = ly; lo[2] = lz;
        }
        {
            int k = lane >> 2, q = lane & 3;
            int idx = nei[pt * K + k];
            const float* fr = feats + (size_t)idx * CMID;
            float4 f0 = *(const float4*)(fr + q * 4);
            float4 f1 = *(const float4*)(fr + 16 + q * 4);
            *(float4*)(&nf[wv][k * CONC + q * 4]) = f0;
            *(float4*)(&nf[wv][k * CONC + 16 + q * 4]) = f1;
        }
        __syncthreads();

        // ---- Stage B1: PE layer 1 (3 -> 32, leaky) ----
        {
            int c = lane & 31, kk = lane >> 5;
            #pragma unroll
            for (int k2 = 0; k2 < 8; ++k2) {
                int k = k2 * 2 + kk;
                float lx = loc_s[wv][k * 3 + 0];
                float ly = loc_s[wv][k * 3 + 1];
                float lz = loc_s[wv][k * 3 + 2];
                float h = pe_b1[c] + lx * pe_w1[c] + ly * pe_w1[32 + c] + lz * pe_w1[64 + c];
                ph_s[wv][k * 32 + c] = lrelu(h);
            }
        }
        __syncthreads();

        // ---- Stage B2: PE layer 2 (32 -> 32, leaky) ----
        {
            int c = lane & 31, kk = lane >> 5;
            #pragma unroll
            for (int k2 = 0; k2 < 8; ++k2) {
                int k = k2 * 2 + kk;
                float acc = pe_b2[c];
                #pragma unroll
                for (int h = 0; h < 32; ++h)
                    acc += ph_s[wv][k * 32 + h] * pe_w2[h * 32 + c];
                nf[wv][k * CONC + 32 + c] = lrelu(acc);
            }
        }
        // ---- WeightNet (3->8 leaky, 8->8 no act, 8->16 leaky), lanes 0..15 serial ----
        if (lane < K) {
            int k = lane;
            float lx = loc_s[wv][k * 3 + 0];
            float ly = loc_s[wv][k * 3 + 1];
            float lz = loc_s[wv][k * 3 + 2];
            float h1[WNH], h2[WNH];
            #pragma unroll
            for (int h = 0; h < WNH; ++h)
                h1[h] = lrelu(wn_b1[h] + lx * wn_w1[h] + ly * wn_w1[WNH + h] + lz * wn_w1[2 * WNH + h]);
            #pragma unroll
            for (int o = 0; o < WNH; ++o) {
                float a = wn_b2[o];
                #pragma unroll
                for (int h = 0; h < WNH; ++h) a += h1[h] * wn_w2[h * WNH + o];
                h2[o] = a;      // no activation on middle layer
            }
            #pragma unroll
            for (int o = 0; o < WNO; ++o) {
                float a = wn_b3[o];
                #pragma unroll
                for (int h = 0; h < WNH; ++h) a += h2[h] * wn_w3[h * WNO + o];
                wnw_s[wv][k * WNO + o] = lrelu(a);
            }
        }
        __syncthreads();

        // ---- Stage C: agg[c][o] = sum_k nf[k][c] * wnw[k][o] ----
        {
            int c = lane;
            float4 acc0 = {0, 0, 0, 0}, acc1 = {0, 0, 0, 0};
            float4 acc2 = {0, 0, 0, 0}, acc3 = {0, 0, 0, 0};
            #pragma unroll
            for (int k = 0; k < K; ++k) {
                float f = nf[wv][k * CONC + c];
                float4 w0 = *(const float4*)(&wnw_s[wv][k * WNO + 0]);
                float4 w1 = *(const float4*)(&wnw_s[wv][k * WNO + 4]);
                float4 w2 = *(const float4*)(&wnw_s[wv][k * WNO + 8]);
                float4 w3 = *(const float4*)(&wnw_s[wv][k * WNO + 12]);
                acc0.x += f * w0.x; acc0.y += f * w0.y; acc0.z += f * w0.z; acc0.w += f * w0.w;
                acc1.x += f * w1.x; acc1.y += f * w1.y; acc1.z += f * w1.z; acc1.w += f * w1.w;
                acc2.x += f * w2.x; acc2.y += f * w2.y; acc2.z += f * w2.z; acc2.w += f * w2.w;
                acc3.x += f * w3.x; acc3.y += f * w3.y; acc3.z += f * w3.z; acc3.w += f * w3.w;
            }
            float* ap = &a_flat[p][c * WNO];
            *(float4*)(ap + 0) = acc0;
            *(float4*)(ap + 4) = acc1;
            *(float4*)(ap + 8) = acc2;
            *(float4*)(ap + 12) = acc3;
        }
        __syncthreads();
    }

    // ---- Stage D: x = leaky(a_flat @ lin_w + lin_b)  (P x 1024) @ (1024 x 64) ----
    {
        int p = tid >> 5;        // 0..7
        int og = tid & 31;       // float2 group over 64 outputs
        int o = og * 2;
        float ax = lin_b[o], ay = lin_b[o + 1];
        for (int j = 0; j < LINI; j += 4) {
            float4 a4 = *(const float4*)(&a_flat[p][j]);
            float2 w0 = *(const float2*)(lin_w + (size_t)(j + 0) * LINO + o);
            float2 w1 = *(const float2*)(lin_w + (size_t)(j + 1) * LINO + o);
            float2 w2 = *(const float2*)(lin_w + (size_t)(j + 2) * LINO + o);
            float2 w3 = *(const float2*)(lin_w + (size_t)(j + 3) * LINO + o);
            ax += a4.x * w0.x + a4.y * w1.x + a4.z * w2.x + a4.w * w3.x;
            ay += a4.x * w0.y + a4.y * w1.y + a4.z * w2.y + a4.w * w3.y;
        }
        xbuf[p][o] = lrelu(ax);
        xbuf[p][o + 1] = lrelu(ay);
    }
    __syncthreads();

    // ---- Stage E: out = leaky(x @ u2_w + u2_b + df_row @ sc_w + sc_b) ----
    {
        int p = tid >> 5;        // 0..7
        int cg = tid & 31;       // float4 group over 128 outputs
        int c = cg * 4;
        int pt = pb + p;
        float4 b0 = *(const float4*)(u2_b + c);
        float4 b1 = *(const float4*)(sc_b + c);
        float4 acc;
        acc.x = b0.x + b1.x; acc.y = b0.y + b1.y; acc.z = b0.z + b1.z; acc.w = b0.w + b1.w;
        const float* frow = df + (size_t)pt * CIN;
        for (int j = 0; j < CIN; ++j) {
            float xv = xbuf[p][j];
            float fv = frow[j];
            float4 w4 = *(const float4*)(u2_w + (size_t)j * COUT + c);
            float4 s4 = *(const float4*)(sc_w + (size_t)j * COUT + c);
            acc.x += xv * w4.x + fv * s4.x;
            acc.y += xv * w4.y + fv * s4.y;
            acc.z += xv * w4.z + fv * s4.z;
            acc.w += xv * w4.w + fv * s4.w;
        }
        acc.x = lrelu(acc.x); acc.y = lrelu(acc.y);
        acc.z = lrelu(acc.z); acc.w = lrelu(acc.w);
        *(float4*)(out + (size_t)pt * COUT + c) = acc;
    }
}

extern "C" void kernel_launch(void* const* d_in, const int* in_sizes, int n_in,
                              void* d_out, int out_size, void* d_ws, size_t ws_size,
                              hipStream_t stream) {
    const float* xyz   = (const float*)d_in[0];
    const float* df    = (const float*)d_in[1];
    const int*   nei   = (const int*)d_in[2];
    const float* pe_w1 = (const float*)d_in[3];
    const float* pe_b1 = (const float*)d_in[4];
    const float* pe_w2 = (const float*)d_in[5];
    const float* pe_b2 = (const float*)d_in[6];
    const float* u1_w  = (const float*)d_in[7];
    const float* u1_b  = (const float*)d_in[8];
    const float* wn_w1 = (const float*)d_in[9];
    const float* wn_b1 = (const float*)d_in[10];
    const float* wn_w2 = (const float*)d_in[11];
    const float* wn_b2 = (const float*)d_in[12];
    const float* wn_w3 = (const float*)d_in[13];
    const float* wn_b3 = (const float*)d_in[14];
    const float* lin_w = (const float*)d_in[15];
    const float* lin_b = (const float*)d_in[16];
    const float* u2_w  = (const float*)d_in[17];
    const float* u2_b  = (const float*)d_in[18];
    const float* sc_w  = (const float*)d_in[19];
    const float* sc_b  = (const float*)d_in[20];

    float* feats = (float*)d_ws;           // N x 32 fp32 = 12.8 MB
    float* outp  = (float*)d_out;

    // Kernel 1: u1 precompute (N*8 threads, 4 outputs each)
    hipLaunchKernelGGL(u1_kernel, dim3((N_PTS * 8 + 255) / 256), dim3(256), 0, stream,
                       df, u1_w, u1_b, feats);

    // Main fused kernel: 8 points per block
    hipLaunchKernelGGL(pc_main_kernel, dim3(N_PTS / P), dim3(256), 0, stream,
                       xyz, df, nei,
                       pe_w1, pe_b1, pe_w2, pe_b2,
                       wn_w1, wn_b1, wn_w2, wn_b2, wn_w3, wn_b3,
                       lin_w, lin_b, u2_w, u2_b, sc_w, sc_b,
                       feats, outp);
}

// Round 2
// 1263.660 us; speedup vs baseline: 1.4789x; 1.4789x over previous
//
#include <hip/hip_runtime.h>
#include <stdint.h>

#define NPTS 100000
#define KNEI 16
#define CIN 64
#define CMID 32
#define CONC 64
#define LINI 1024
#define LINO 64
#define COUT 128

typedef unsigned short u16;
typedef unsigned int u32;
typedef __attribute__((ext_vector_type(8))) short bf16x8;
typedef __attribute__((ext_vector_type(4))) float f32x4;

// ws layout (bytes):
//   [0, 6400000)          feats bf16, N x 32
//   [6400000, 6531072)    packed lin_w bf16 (65536 elems, MFMA B-fragment order)
//   [6531072, ...)        agg bf16, CH x 1024 per chunk
#define WS_PACKB 6400000
#define WS_AGG   6531072

__device__ __forceinline__ float lrelu(float x) { return x > 0.f ? x : 0.1f * x; }

__device__ __forceinline__ u32 f2bf(float f) {
    union { float f; u32 u; } v; v.f = f;
    return (v.u + 0x7FFFu + ((v.u >> 16) & 1u)) >> 16;   // RNE
}
__device__ __forceinline__ float bf2f(u32 h) {
    union { u32 u; float f; } v; v.u = h << 16; return v.f;
}

// ---- K1a: feats = bf16(dense_feats @ u1_w + u1_b), N x 32 ----
__global__ __launch_bounds__(256) void k_u1(const float* __restrict__ df,
                                            const float* __restrict__ w,
                                            const float* __restrict__ b,
                                            u16* __restrict__ feats) {
    int t = blockIdx.x * 256 + threadIdx.x;
    int n = t >> 3, g = t & 7;
    if (n >= NPTS) return;
    int c = g * 4;
    float4 acc = *(const float4*)(b + c);
    const float* row = df + (size_t)n * CIN;
    #pragma unroll
    for (int j = 0; j < CIN; j += 4) {
        float4 f = *(const float4*)(row + j);
        float4 w0 = *(const float4*)(w + (j + 0) * CMID + c);
        float4 w1 = *(const float4*)(w + (j + 1) * CMID + c);
        float4 w2 = *(const float4*)(w + (j + 2) * CMID + c);
        float4 w3 = *(const float4*)(w + (j + 3) * CMID + c);
        acc.x += f.x * w0.x + f.y * w1.x + f.z * w2.x + f.w * w3.x;
        acc.y += f.x * w0.y + f.y * w1.y + f.z * w2.y + f.w * w3.y;
        acc.z += f.x * w0.z + f.y * w1.z + f.z * w2.z + f.w * w3.z;
        acc.w += f.x * w0.w + f.y * w1.w + f.z * w2.w + f.w * w3.w;
    }
    uint2 o;
    o.x = f2bf(acc.x) | (f2bf(acc.y) << 16);
    o.y = f2bf(acc.z) | (f2bf(acc.w) << 16);
    *(uint2*)(feats + (size_t)n * CMID + c) = o;
}

// ---- K1b: pack lin_w (1024x64 fp32) -> bf16 in MFMA B-fragment lane order ----
// slot s = kb*4+nt holds 64 lanes x 8 bf16; lane=(quad*16+n):
//   elem (lane,j) = lin_w[(kb*32+quad*8+j)*64 + nt*16+n]
__global__ __launch_bounds__(256) void k_pack(const float* __restrict__ lin_w,
                                              u16* __restrict__ packB) {
    int t = blockIdx.x * 256 + threadIdx.x;     // 65536 total
    int j = t & 7, ln = (t >> 3) & 63, s = t >> 9;
    int nt = s & 3, kb = s >> 2;
    int k = kb * 32 + (ln >> 4) * 8 + j;
    int n = nt * 16 + (ln & 15);
    packB[t] = (u16)f2bf(lin_w[k * 64 + n]);
}

// ---- K2: per point (one wave each): gather, PE, WeightNet, aggregate ----
__global__ __launch_bounds__(256) void k2_point(
    const float* __restrict__ xyz, const int* __restrict__ nei,
    const u16* __restrict__ feats,
    const float* __restrict__ pe_w1, const float* __restrict__ pe_b1,
    const float* __restrict__ pe_w2, const float* __restrict__ pe_b2,
    const float* __restrict__ wn_w1, const float* __restrict__ wn_b1,
    const float* __restrict__ wn_w2, const float* __restrict__ wn_b2,
    const float* __restrict__ wn_w3, const float* __restrict__ wn_b3,
    u16* __restrict__ agg, float* __restrict__ locout, int c0)
{
    __shared__ float nf_s[4][16 * 64];    // 16 KB (new_feat: 0..31 gathered feats, 32..63 pe)
    __shared__ float ph_s[4][16 * 32];    //  8 KB
    __shared__ float wnw_s[4][16 * 16];   //  4 KB
    __shared__ float loc_s[4][48];        // .75 KB
    const int tid = threadIdx.x, wv = tid >> 6, lane = tid & 63;
    const int pt = c0 + blockIdx.x * 4 + wv;

    // Stage A: localized coords (also output 2) + neighbor feats gather
    if (lane < KNEI) {
        int idx = nei[pt * KNEI + lane];
        float cx = xyz[pt * 3 + 0], cy = xyz[pt * 3 + 1], cz = xyz[pt * 3 + 2];
        float lx = xyz[idx * 3 + 0] - cx;
        float ly = xyz[idx * 3 + 1] - cy;
        float lz = xyz[idx * 3 + 2] - cz;
        loc_s[wv][lane * 3 + 0] = lx;
        loc_s[wv][lane * 3 + 1] = ly;
        loc_s[wv][lane * 3 + 2] = lz;
        float* lo = locout + (size_t)(pt * KNEI + lane) * 3;
        lo[0] = lx; lo[1] = ly; lo[2] = lz;
    }
    {
        int k = lane >> 2, q = lane & 3;
        int idx = nei[pt * KNEI + k];
        uint4 v = *(const uint4*)(feats + (size_t)idx * CMID + q * 8);
        float* dst = &nf_s[wv][k * CONC + q * 8];
        dst[0] = bf2f(v.x & 0xffff); dst[1] = bf2f(v.x >> 16);
        dst[2] = bf2f(v.y & 0xffff); dst[3] = bf2f(v.y >> 16);
        dst[4] = bf2f(v.z & 0xffff); dst[5] = bf2f(v.z >> 16);
        dst[6] = bf2f(v.w & 0xffff); dst[7] = bf2f(v.w >> 16);
    }
    __syncthreads();

    // B1: PE layer 1 (3->32, leaky)
    {
        int c = lane & 31, kk = lane >> 5;
        float w0 = pe_w1[c], w1 = pe_w1[32 + c], w2 = pe_w1[64 + c], b = pe_b1[c];
        #pragma unroll
        for (int k2 = 0; k2 < 8; ++k2) {
            int k = k2 * 2 + kk;
            float lx = loc_s[wv][k * 3 + 0];
            float ly = loc_s[wv][k * 3 + 1];
            float lz = loc_s[wv][k * 3 + 2];
            ph_s[wv][k * 32 + c] = lrelu(b + lx * w0 + ly * w1 + lz * w2);
        }
    }
    __syncthreads();

    // B2: PE layer 2 (32->32, leaky)
    {
        int c = lane & 31, kk = lane >> 5;
        float b2 = pe_b2[c];
        #pragma unroll
        for (int k2 = 0; k2 < 8; ++k2) {
            int k = k2 * 2 + kk;
            float acc = b2;
            #pragma unroll
            for (int h = 0; h < 32; ++h)
                acc += ph_s[wv][k * 32 + h] * pe_w2[h * 32 + c];
            nf_s[wv][k * CONC + 32 + c] = lrelu(acc);
        }
    }
    // WeightNet (3->8 leaky, 8->8 none, 8->16 leaky), one neighbor per lane<16
    if (lane < KNEI) {
        int k = lane;
        float lx = loc_s[wv][k * 3 + 0];
        float ly = loc_s[wv][k * 3 + 1];
        float lz = loc_s[wv][k * 3 + 2];
        float h1[8], h2[8];
        #pragma unroll
        for (int h = 0; h < 8; ++h)
            h1[h] = lrelu(wn_b1[h] + lx * wn_w1[h] + ly * wn_w1[8 + h] + lz * wn_w1[16 + h]);
        #pragma unroll
        for (int o = 0; o < 8; ++o) {
            float a = wn_b2[o];
            #pragma unroll
            for (int h = 0; h < 8; ++h) a += h1[h] * wn_w2[h * 8 + o];
            h2[o] = a;
        }
        #pragma unroll
        for (int o = 0; o < 16; ++o) {
            float a = wn_b3[o];
            #pragma unroll
            for (int h = 0; h < 8; ++h) a += h2[h] * wn_w3[h * 16 + o];
            wnw_s[wv][k * 16 + o] = lrelu(a);
        }
    }
    __syncthreads();

    // Stage C: agg[c*16+o] = sum_k nf[k][c] * wnw[k][o]; write bf16 row
    {
        int c = lane;
        float acc[16];
        #pragma unroll
        for (int i = 0; i < 16; ++i) acc[i] = 0.f;
        #pragma unroll
        for (int k = 0; k < KNEI; ++k) {
            float f = nf_s[wv][k * CONC + c];
            float4 w0 = *(const float4*)(&wnw_s[wv][k * 16 + 0]);
            float4 w1 = *(const float4*)(&wnw_s[wv][k * 16 + 4]);
            float4 w2 = *(const float4*)(&wnw_s[wv][k * 16 + 8]);
            float4 w3 = *(const float4*)(&wnw_s[wv][k * 16 + 12]);
            acc[0] += f * w0.x;  acc[1] += f * w0.y;  acc[2] += f * w0.z;  acc[3] += f * w0.w;
            acc[4] += f * w1.x;  acc[5] += f * w1.y;  acc[6] += f * w1.z;  acc[7] += f * w1.w;
            acc[8] += f * w2.x;  acc[9] += f * w2.y;  acc[10] += f * w2.z; acc[11] += f * w2.w;
            acc[12] += f * w3.x; acc[13] += f * w3.y; acc[14] += f * w3.z; acc[15] += f * w3.w;
        }
        u16* dst = agg + (size_t)(pt - c0) * LINI + c * 16;
        uint4 o1, o2;
        o1.x = f2bf(acc[0])  | (f2bf(acc[1])  << 16);
        o1.y = f2bf(acc[2])  | (f2bf(acc[3])  << 16);
        o1.z = f2bf(acc[4])  | (f2bf(acc[5])  << 16);
        o1.w = f2bf(acc[6])  | (f2bf(acc[7])  << 16);
        o2.x = f2bf(acc[8])  | (f2bf(acc[9])  << 16);
        o2.y = f2bf(acc[10]) | (f2bf(acc[11]) << 16);
        o2.z = f2bf(acc[12]) | (f2bf(acc[13]) << 16);
        o2.w = f2bf(acc[14]) | (f2bf(acc[15]) << 16);
        *(uint4*)dst = o1;
        *(uint4*)(dst + 8) = o2;
    }
}

// ---- K3: x = lrelu(agg @ lin_w + lin_b) via MFMA; then u2 + shortcut epilogue ----
__global__ __launch_bounds__(256) void k3_gemm(
    const u16* __restrict__ agg, const u16* __restrict__ packB,
    const float* __restrict__ lin_b,
    const float* __restrict__ u2_w, const float* __restrict__ u2_b,
    const float* __restrict__ sc_w, const float* __restrict__ sc_b,
    const float* __restrict__ df, float* __restrict__ out,
    int c0, int chc)
{
    __shared__ float xbuf[64][68];
    const int tid = threadIdx.x, wv = tid >> 6, lane = tid & 63;
    const int quad = lane >> 4, nl = lane & 15;
    const int mloc = blockIdx.x * 64 + wv * 16;

    const u16* arow = agg + (size_t)(mloc + nl) * LINI + quad * 8;
    const u16* bp = packB + lane * 8;

    f32x4 accs[4];
    #pragma unroll
    for (int nt = 0; nt < 4; ++nt) accs[nt] = (f32x4){0.f, 0.f, 0.f, 0.f};

    #pragma unroll 2
    for (int kb = 0; kb < 32; ++kb) {
        bf16x8 a = *(const bf16x8*)(arow + kb * 32);
        bf16x8 b0 = *(const bf16x8*)(bp + (kb * 4 + 0) * 512);
        bf16x8 b1 = *(const bf16x8*)(bp + (kb * 4 + 1) * 512);
        bf16x8 b2 = *(const bf16x8*)(bp + (kb * 4 + 2) * 512);
        bf16x8 b3 = *(const bf16x8*)(bp + (kb * 4 + 3) * 512);
        accs[0] = __builtin_amdgcn_mfma_f32_16x16x32_bf16(a, b0, accs[0], 0, 0, 0);
        accs[1] = __builtin_amdgcn_mfma_f32_16x16x32_bf16(a, b1, accs[1], 0, 0, 0);
        accs[2] = __builtin_amdgcn_mfma_f32_16x16x32_bf16(a, b2, accs[2], 0, 0, 0);
        accs[3] = __builtin_amdgcn_mfma_f32_16x16x32_bf16(a, b3, accs[3], 0, 0, 0);
    }

    // epilogue: +lin_b, lrelu, to LDS.  C/D layout: col=lane&15, row=quad*4+reg
    #pragma unroll
    for (int nt = 0; nt < 4; ++nt) {
        int col = nt * 16 + nl;
        float lb = lin_b[col];
        #pragma unroll
        for (int r = 0; r < 4; ++r)
            xbuf[wv * 16 + quad * 4 + r][col] = lrelu(accs[nt][r] + lb);
    }
    __syncthreads();

    // Stage E: out = lrelu(x @ u2_w + u2_b + df @ sc_w + sc_b)
    {
        int p = tid >> 2, cb = (tid & 3) * 32;
        int pt = c0 + blockIdx.x * 64 + p;
        bool ok = (blockIdx.x * 64 + p) < chc;
        int ptc = ok ? pt : c0;
        float acc[32];
        #pragma unroll
        for (int i = 0; i < 8; ++i) {
            float4 b0 = *(const float4*)(u2_b + cb + i * 4);
            float4 b1 = *(const float4*)(sc_b + cb + i * 4);
            acc[i * 4 + 0] = b0.x + b1.x;
            acc[i * 4 + 1] = b0.y + b1.y;
            acc[i * 4 + 2] = b0.z + b1.z;
            acc[i * 4 + 3] = b0.w + b1.w;
        }
        const float* frow = df + (size_t)ptc * CIN;
        for (int j = 0; j < CIN; ++j) {
            float xv = xbuf[p][j];
            float fv = frow[j];
            const float* ur = u2_w + (size_t)j * COUT + cb;
            const float* sr = sc_w + (size_t)j * COUT + cb;
            #pragma unroll
            for (int i = 0; i < 8; ++i) {
                float4 u4 = *(const float4*)(ur + i * 4);
                float4 s4 = *(const float4*)(sr + i * 4);
                acc[i * 4 + 0] += xv * u4.x + fv * s4.x;
                acc[i * 4 + 1] += xv * u4.y + fv * s4.y;
                acc[i * 4 + 2] += xv * u4.z + fv * s4.z;
                acc[i * 4 + 3] += xv * u4.w + fv * s4.w;
            }
        }
        if (ok) {
            float* orow = out + (size_t)pt * COUT + cb;
            #pragma unroll
            for (int i = 0; i < 8; ++i) {
                float4 o;
                o.x = lrelu(acc[i * 4 + 0]);
                o.y = lrelu(acc[i * 4 + 1]);
                o.z = lrelu(acc[i * 4 + 2]);
                o.w = lrelu(acc[i * 4 + 3]);
                *(float4*)(orow + i * 4) = o;
            }
        }
    }
}

extern "C" void kernel_launch(void* const* d_in, const int* in_sizes, int n_in,
                              void* d_out, int out_size, void* d_ws, size_t ws_size,
                              hipStream_t stream) {
    const float* xyz   = (const float*)d_in[0];
    const float* df    = (const float*)d_in[1];
    const int*   nei   = (const int*)d_in[2];
    const float* pe_w1 = (const float*)d_in[3];
    const float* pe_b1 = (const float*)d_in[4];
    const float* pe_w2 = (const float*)d_in[5];
    const float* pe_b2 = (const float*)d_in[6];
    const float* u1_w  = (const float*)d_in[7];
    const float* u1_b  = (const float*)d_in[8];
    const float* wn_w1 = (const float*)d_in[9];
    const float* wn_b1 = (const float*)d_in[10];
    const float* wn_w2 = (const float*)d_in[11];
    const float* wn_b2 = (const float*)d_in[12];
    const float* wn_w3 = (const float*)d_in[13];
    const float* wn_b3 = (const float*)d_in[14];
    const float* lin_w = (const float*)d_in[15];
    const float* lin_b = (const float*)d_in[16];
    const float* u2_w  = (const float*)d_in[17];
    const float* u2_b  = (const float*)d_in[18];
    const float* sc_w  = (const float*)d_in[19];
    const float* sc_b  = (const float*)d_in[20];

    u16* feats = (u16*)d_ws;
    u16* packB = (u16*)((char*)d_ws + WS_PACKB);
    u16* agg   = (u16*)((char*)d_ws + WS_AGG);
    float* outp = (float*)d_out;
    float* locout = outp + (size_t)NPTS * COUT;

    // chunk size from ws_size (deterministic per session -> graph-safe)
    size_t avail = ws_size > (size_t)WS_AGG ? ws_size - (size_t)WS_AGG : 0;
    long long ch = (long long)(avail / (LINI * 2));
    ch &= ~63LL;                       // multiple of 64
    if (ch > 100032) ch = 100032;      // one chunk covers all points (padded)
    if (ch < 64) ch = 64;

    hipLaunchKernelGGL(k_u1, dim3((NPTS * 8 + 255) / 256), dim3(256), 0, stream,
                       df, u1_w, u1_b, feats);
    hipLaunchKernelGGL(k_pack, dim3(65536 / 256), dim3(256), 0, stream, lin_w, packB);

    for (int c0 = 0; c0 < NPTS; c0 += (int)ch) {
        int chc = NPTS - c0 < (int)ch ? NPTS - c0 : (int)ch;   // multiple of 4
        hipLaunchKernelGGL(k2_point, dim3(chc / 4), dim3(256), 0, stream,
                           xyz, nei, feats,
                           pe_w1, pe_b1, pe_w2, pe_b2,
                           wn_w1, wn_b1, wn_w2, wn_b2, wn_w3, wn_b3,
                           agg, locout, c0);
        hipLaunchKernelGGL(k3_gemm, dim3((chc + 63) / 64), dim3(256), 0, stream,
                           agg, packB, lin_b, u2_w, u2_b, sc_w, sc_b,
                           df, outp, c0, chc);
    }
}

// Round 3
// 582.922 us; speedup vs baseline: 3.2061x; 2.1678x over previous
//
#include <hip/hip_runtime.h>
#include <stdint.h>

#define NPTS 100000
#define KNEI 16
#define CIN 64
#define CMID 32
#define CONC 64
#define LINI 1024
#define COUT 128

typedef unsigned short u16;
typedef unsigned int u32;
typedef __attribute__((ext_vector_type(8))) short bf16x8;
typedef __attribute__((ext_vector_type(4))) float f32x4;

// ws layout (bytes):
//   [0, 6400000)            feats bf16, N x 32
//   [WS_PACKB, +131072)     packed lin_w bf16 (65536 elems, MFMA B-frag order)
//   [WS_PACKW2, +32768)     packed [u2_w; sc_w] bf16 (16384 elems, B-frag order)
//   [WS_AGG, ...)           agg bf16 in MFMA A-frag order: [grp][kb][64][8]
#define WS_PACKB  6400000
#define WS_PACKW2 (WS_PACKB + 131072)
#define WS_AGG    (WS_PACKW2 + 32768)

__device__ __forceinline__ float lrelu(float x) { return x > 0.f ? x : 0.1f * x; }

__device__ __forceinline__ u32 f2bf(float f) {
    union { float f; u32 u; } v; v.f = f;
    return (v.u + 0x7FFFu + ((v.u >> 16) & 1u)) >> 16;   // RNE
}
__device__ __forceinline__ float bf2f(u32 h) {
    union { u32 u; float f; } v; v.u = h << 16; return v.f;
}

// ---- K1a: feats = bf16(dense_feats @ u1_w + u1_b), N x 32 ----
__global__ __launch_bounds__(256) void k_u1(const float* __restrict__ df,
                                            const float* __restrict__ w,
                                            const float* __restrict__ b,
                                            u16* __restrict__ feats) {
    int t = blockIdx.x * 256 + threadIdx.x;
    int n = t >> 3, g = t & 7;
    if (n >= NPTS) return;
    int c = g * 4;
    float4 acc = *(const float4*)(b + c);
    const float* row = df + (size_t)n * CIN;
    #pragma unroll
    for (int j = 0; j < CIN; j += 4) {
        float4 f = *(const float4*)(row + j);
        float4 w0 = *(const float4*)(w + (j + 0) * CMID + c);
        float4 w1 = *(const float4*)(w + (j + 1) * CMID + c);
        float4 w2 = *(const float4*)(w + (j + 2) * CMID + c);
        float4 w3 = *(const float4*)(w + (j + 3) * CMID + c);
        acc.x += f.x * w0.x + f.y * w1.x + f.z * w2.x + f.w * w3.x;
        acc.y += f.x * w0.y + f.y * w1.y + f.z * w2.y + f.w * w3.y;
        acc.z += f.x * w0.z + f.y * w1.z + f.z * w2.z + f.w * w3.z;
        acc.w += f.x * w0.w + f.y * w1.w + f.z * w2.w + f.w * w3.w;
    }
    uint2 o;
    o.x = f2bf(acc.x) | (f2bf(acc.y) << 16);
    o.y = f2bf(acc.z) | (f2bf(acc.w) << 16);
    *(uint2*)(feats + (size_t)n * CMID + c) = o;
}

// ---- K1b: pack lin_w (1024x64 fp32) -> bf16 MFMA B-frag order ----
// slot s = kb*4+nt (512 elems): elem(lane=q*16+n, j) = lin_w[(kb*32+q*8+j)*64 + nt*16+n]
__global__ __launch_bounds__(256) void k_pack(const float* __restrict__ lin_w,
                                              u16* __restrict__ packB) {
    int t = blockIdx.x * 256 + threadIdx.x;     // 65536 total
    int j = t & 7, ln = (t >> 3) & 63, s = t >> 9;
    int nt = s & 3, kb = s >> 2;
    int k = kb * 32 + (ln >> 4) * 8 + j;
    int n = nt * 16 + (ln & 15);
    packB[t] = (u16)f2bf(lin_w[k * 64 + n]);
}

// ---- K1c: pack W2 = [u2_w; sc_w] (128x128) -> bf16 B-frag order ----
// slot s = kb2*8+nt2 (512 elems): elem(lane=q*16+n, j) = W2[kb2*32+q*8+j][nt2*16+n]
__global__ __launch_bounds__(256) void k_packW2(const float* __restrict__ u2_w,
                                                const float* __restrict__ sc_w,
                                                u16* __restrict__ packW2) {
    int t = blockIdx.x * 256 + threadIdx.x;     // 16384 total
    int j = t & 7, ln = (t >> 3) & 63, s = t >> 9;
    int nt2 = s & 7, kb2 = s >> 3;
    int k = kb2 * 32 + (ln >> 4) * 8 + j;
    int n = nt2 * 16 + (ln & 15);
    float v = (k < 64) ? u2_w[k * COUT + n] : sc_w[(k - 64) * COUT + n];
    packW2[t] = (u16)f2bf(v);
}

// ---- K2: one wave per point: gather, PE, WeightNet, aggregate ----
__global__ __launch_bounds__(64) void k2_point(
    const float* __restrict__ xyz, const int* __restrict__ nei,
    const u16* __restrict__ feats,
    const float* __restrict__ pe_w1, const float* __restrict__ pe_b1,
    const float* __restrict__ pe_w2, const float* __restrict__ pe_b2,
    const float* __restrict__ wn_w1, const float* __restrict__ wn_b1,
    const float* __restrict__ wn_w2, const float* __restrict__ wn_b2,
    const float* __restrict__ wn_w3, const float* __restrict__ wn_b3,
    u16* __restrict__ agg, float* __restrict__ locout, int c0)
{
    __shared__ float nf_s[16 * 64];
    __shared__ float ph_s[16 * 32];
    __shared__ float wnw_s[16 * 16];
    __shared__ float loc_s[48];
    const int lane = threadIdx.x;
    const int pt = c0 + blockIdx.x;

    // Stage A: localized coords (output 2) + neighbor feats gather
    if (lane < KNEI) {
        int idx = nei[pt * KNEI + lane];
        float cx = xyz[pt * 3 + 0], cy = xyz[pt * 3 + 1], cz = xyz[pt * 3 + 2];
        float lx = xyz[idx * 3 + 0] - cx;
        float ly = xyz[idx * 3 + 1] - cy;
        float lz = xyz[idx * 3 + 2] - cz;
        loc_s[lane * 3 + 0] = lx;
        loc_s[lane * 3 + 1] = ly;
        loc_s[lane * 3 + 2] = lz;
        float* lo = locout + (size_t)(pt * KNEI + lane) * 3;
        lo[0] = lx; lo[1] = ly; lo[2] = lz;
    }
    {
        int k = lane >> 2, q = lane & 3;
        int idx = nei[pt * KNEI + k];
        uint4 v = *(const uint4*)(feats + (size_t)idx * CMID + q * 8);
        float* dst = &nf_s[k * CONC + q * 8];
        dst[0] = bf2f(v.x & 0xffff); dst[1] = bf2f(v.x >> 16);
        dst[2] = bf2f(v.y & 0xffff); dst[3] = bf2f(v.y >> 16);
        dst[4] = bf2f(v.z & 0xffff); dst[5] = bf2f(v.z >> 16);
        dst[6] = bf2f(v.w & 0xffff); dst[7] = bf2f(v.w >> 16);
    }
    __syncthreads();

    // B1: PE layer 1 (3->32, leaky)
    {
        int c = lane & 31, kk = lane >> 5;
        float w0 = pe_w1[c], w1 = pe_w1[32 + c], w2 = pe_w1[64 + c], b = pe_b1[c];
        #pragma unroll
        for (int k2 = 0; k2 < 8; ++k2) {
            int k = k2 * 2 + kk;
            float lx = loc_s[k * 3 + 0];
            float ly = loc_s[k * 3 + 1];
            float lz = loc_s[k * 3 + 2];
            ph_s[k * 32 + c] = lrelu(b + lx * w0 + ly * w1 + lz * w2);
        }
    }
    __syncthreads();

    // B2: PE layer 2 (32->32, leaky)
    {
        int c = lane & 31, kk = lane >> 5;
        float b2 = pe_b2[c];
        #pragma unroll
        for (int k2 = 0; k2 < 8; ++k2) {
            int k = k2 * 2 + kk;
            float acc = b2;
            #pragma unroll
            for (int h = 0; h < 32; ++h)
                acc += ph_s[k * 32 + h] * pe_w2[h * 32 + c];
            nf_s[k * CONC + 32 + c] = lrelu(acc);
        }
    }
    // WeightNet (3->8 leaky, 8->8 none, 8->16 leaky)
    if (lane < KNEI) {
        int k = lane;
        float lx = loc_s[k * 3 + 0];
        float ly = loc_s[k * 3 + 1];
        float lz = loc_s[k * 3 + 2];
        float h1[8], h2[8];
        #pragma unroll
        for (int h = 0; h < 8; ++h)
            h1[h] = lrelu(wn_b1[h] + lx * wn_w1[h] + ly * wn_w1[8 + h] + lz * wn_w1[16 + h]);
        #pragma unroll
        for (int o = 0; o < 8; ++o) {
            float a = wn_b2[o];
            #pragma unroll
            for (int h = 0; h < 8; ++h) a += h1[h] * wn_w2[h * 8 + o];
            h2[o] = a;
        }
        #pragma unroll
        for (int o = 0; o < 16; ++o) {
            float a = wn_b3[o];
            #pragma unroll
            for (int h = 0; h < 8; ++h) a += h2[h] * wn_w3[h * 16 + o];
            wnw_s[k * 16 + o] = lrelu(a);
        }
    }
    __syncthreads();

    // Stage C: agg row elements e=c*16+o; store in A-frag order:
    // e = kb*32 + q*8 + j, dst = ((g*32+kb)*64 + q*16 + nl)*8 + j
    {
        int c = lane;
        float acc[16];
        #pragma unroll
        for (int i = 0; i < 16; ++i) acc[i] = 0.f;
        #pragma unroll
        for (int k = 0; k < KNEI; ++k) {
            float f = nf_s[k * CONC + c];
            float4 w0 = *(const float4*)(&wnw_s[k * 16 + 0]);
            float4 w1 = *(const float4*)(&wnw_s[k * 16 + 4]);
            float4 w2 = *(const float4*)(&wnw_s[k * 16 + 8]);
            float4 w3 = *(const float4*)(&wnw_s[k * 16 + 12]);
            acc[0] += f * w0.x;  acc[1] += f * w0.y;  acc[2] += f * w0.z;  acc[3] += f * w0.w;
            acc[4] += f * w1.x;  acc[5] += f * w1.y;  acc[6] += f * w1.z;  acc[7] += f * w1.w;
            acc[8] += f * w2.x;  acc[9] += f * w2.y;  acc[10] += f * w2.z; acc[11] += f * w2.w;
            acc[12] += f * w3.x; acc[13] += f * w3.y; acc[14] += f * w3.z; acc[15] += f * w3.w;
        }
        int g = (pt - c0) >> 4, nl = pt & 15;
        int kb = c >> 1, qb = (c & 1) * 2;
        uint4 o1, o2;
        o1.x = f2bf(acc[0])  | (f2bf(acc[1])  << 16);
        o1.y = f2bf(acc[2])  | (f2bf(acc[3])  << 16);
        o1.z = f2bf(acc[4])  | (f2bf(acc[5])  << 16);
        o1.w = f2bf(acc[6])  | (f2bf(acc[7])  << 16);
        o2.x = f2bf(acc[8])  | (f2bf(acc[9])  << 16);
        o2.y = f2bf(acc[10]) | (f2bf(acc[11]) << 16);
        o2.z = f2bf(acc[12]) | (f2bf(acc[13]) << 16);
        o2.w = f2bf(acc[14]) | (f2bf(acc[15]) << 16);
        u16* base = agg + ((size_t)(g * 32 + kb) * 64) * 8;
        *(uint4*)(base + (qb * 16 + nl) * 8) = o1;
        *(uint4*)(base + ((qb + 1) * 16 + nl) * 8) = o2;
    }
}

// ---- K3: GEMM1 (agg @ lin_w, MFMA) -> x; GEMM2 ([x|df] @ [u2_w;sc_w], MFMA) -> out
__global__ __launch_bounds__(256) void k3_gemm(
    const u16* __restrict__ agg, const u16* __restrict__ packB,
    const u16* __restrict__ packW2,
    const float* __restrict__ lin_b,
    const float* __restrict__ u2_b, const float* __restrict__ sc_b,
    const float* __restrict__ df, float* __restrict__ out,
    int c0, int chc)
{
    __shared__ __align__(16) char lds[65536];
    u16* regA = (u16*)lds;           // [0,32K): GEMM1 B superchunk (16K) then W2 (32K)
    u16* xd   = (u16*)(lds + 32768); // [32K,64K): [x|df] in A-frag order [g8][kb2][64][8]

    const int tid = threadIdx.x, wv = tid >> 6, lane = tid & 63;
    const int quad = lane >> 4, nl = lane & 15;
    const int gmax = (chc - 1) >> 4;
    const int gblk = blockIdx.x * 8;
    int g0 = gblk + wv * 2, g1 = g0 + 1;
    int g0c = g0 > gmax ? gmax : g0, g1c = g1 > gmax ? gmax : g1;

    const u16* a0p = agg + (size_t)g0c * 32 * 512 + lane * 8;
    const u16* a1p = agg + (size_t)g1c * 32 * 512 + lane * 8;

    f32x4 acc[2][4];
    #pragma unroll
    for (int m = 0; m < 2; ++m)
        #pragma unroll
        for (int nt = 0; nt < 4; ++nt) acc[m][nt] = (f32x4){0.f, 0.f, 0.f, 0.f};

    // prefetch B superchunk 0 to regs, A kb=0
    uint4 st0, st1, st2, st3;
    {
        const uint4* src = (const uint4*)packB + tid;
        st0 = src[0]; st1 = src[256]; st2 = src[512]; st3 = src[768];
    }
    bf16x8 a0n = *(const bf16x8*)a0p;
    bf16x8 a1n = *(const bf16x8*)a1p;

    for (int sc = 0; sc < 8; ++sc) {
        __syncthreads();
        uint4* bb = (uint4*)regA;
        bb[tid] = st0; bb[tid + 256] = st1; bb[tid + 512] = st2; bb[tid + 768] = st3;
        __syncthreads();
        if (sc < 7) {
            const uint4* src = (const uint4*)(packB + (size_t)(sc + 1) * 8192) + tid;
            st0 = src[0]; st1 = src[256]; st2 = src[512]; st3 = src[768];
        }
        #pragma unroll
        for (int kbL = 0; kbL < 4; ++kbL) {
            int kb = sc * 4 + kbL;
            bf16x8 a0 = a0n, a1 = a1n;
            int kn = kb < 31 ? kb + 1 : 31;
            a0n = *(const bf16x8*)(a0p + (size_t)kn * 512);
            a1n = *(const bf16x8*)(a1p + (size_t)kn * 512);
            const u16* bp = regA + kbL * 2048 + lane * 8;
            bf16x8 b0 = *(const bf16x8*)(bp);
            bf16x8 b1 = *(const bf16x8*)(bp + 512);
            bf16x8 b2 = *(const bf16x8*)(bp + 1024);
            bf16x8 b3 = *(const bf16x8*)(bp + 1536);
            acc[0][0] = __builtin_amdgcn_mfma_f32_16x16x32_bf16(a0, b0, acc[0][0], 0, 0, 0);
            acc[1][0] = __builtin_amdgcn_mfma_f32_16x16x32_bf16(a1, b0, acc[1][0], 0, 0, 0);
            acc[0][1] = __builtin_amdgcn_mfma_f32_16x16x32_bf16(a0, b1, acc[0][1], 0, 0, 0);
            acc[1][1] = __builtin_amdgcn_mfma_f32_16x16x32_bf16(a1, b1, acc[1][1], 0, 0, 0);
            acc[0][2] = __builtin_amdgcn_mfma_f32_16x16x32_bf16(a0, b2, acc[0][2], 0, 0, 0);
            acc[1][2] = __builtin_amdgcn_mfma_f32_16x16x32_bf16(a1, b2, acc[1][2], 0, 0, 0);
            acc[0][3] = __builtin_amdgcn_mfma_f32_16x16x32_bf16(a0, b3, acc[0][3], 0, 0, 0);
            acc[1][3] = __builtin_amdgcn_mfma_f32_16x16x32_bf16(a1, b3, acc[1][3], 0, 0, 0);
        }
    }

    __syncthreads();   // all GEMM1 LDS reads done

    // stage W2 into regA (32 KB)
    {
        const uint4* src = (const uint4*)packW2;
        uint4* dst = (uint4*)regA;
        #pragma unroll
        for (int i = 0; i < 8; ++i) dst[i * 256 + tid] = src[i * 256 + tid];
    }
    // x -> xd (cols 0..63), bf16, A-frag order
    #pragma unroll
    for (int m = 0; m < 2; ++m) {
        int g8 = wv * 2 + m;
        #pragma unroll
        for (int nt = 0; nt < 4; ++nt) {
            int colk = nt * 16 + nl;
            float lb = lin_b[colk];
            int kb2 = colk >> 5, q2 = (colk >> 3) & 3, j2 = colk & 7;
            #pragma unroll
            for (int r = 0; r < 4; ++r) {
                int row16 = quad * 4 + r;
                float v = lrelu(acc[m][nt][r] + lb);
                xd[((g8 * 4 + kb2) * 64 + q2 * 16 + row16) * 8 + j2] = (u16)f2bf(v);
            }
        }
    }
    // df -> xd (cols 64..127)
    {
        int row = tid >> 1, half = tid & 1;
        int ptl = gblk * 16 + row;
        int ptc = ptl < chc ? (c0 + ptl) : c0;
        int g8 = row >> 4, row16 = row & 15;
        const float* dfr = df + (size_t)ptc * CIN + half * 32;
        #pragma unroll
        for (int jj = 0; jj < 32; jj += 8) {
            float4 f0 = *(const float4*)(dfr + jj);
            float4 f1 = *(const float4*)(dfr + jj + 4);
            int colk = 64 + half * 32 + jj;
            int kb2 = colk >> 5, q2 = (colk >> 3) & 3;
            uint4 o;
            o.x = f2bf(f0.x) | (f2bf(f0.y) << 16);
            o.y = f2bf(f0.z) | (f2bf(f0.w) << 16);
            o.z = f2bf(f1.x) | (f2bf(f1.y) << 16);
            o.w = f2bf(f1.z) | (f2bf(f1.w) << 16);
            *(uint4*)(xd + ((g8 * 4 + kb2) * 64 + q2 * 16 + row16) * 8) = o;
        }
    }
    __syncthreads();

    // GEMM2: [x|df] (128x128) @ W2 (128x128)
    f32x4 acc2[2][8];
    #pragma unroll
    for (int m = 0; m < 2; ++m)
        #pragma unroll
        for (int nt = 0; nt < 8; ++nt) acc2[m][nt] = (f32x4){0.f, 0.f, 0.f, 0.f};
    #pragma unroll
    for (int kb2 = 0; kb2 < 4; ++kb2) {
        bf16x8 a0 = *(const bf16x8*)(xd + ((size_t)((wv * 2 + 0) * 4 + kb2)) * 512 + lane * 8);
        bf16x8 a1 = *(const bf16x8*)(xd + ((size_t)((wv * 2 + 1) * 4 + kb2)) * 512 + lane * 8);
        #pragma unroll
        for (int nt = 0; nt < 8; ++nt) {
            bf16x8 b = *(const bf16x8*)(regA + (kb2 * 8 + nt) * 512 + lane * 8);
            acc2[0][nt] = __builtin_amdgcn_mfma_f32_16x16x32_bf16(a0, b, acc2[0][nt], 0, 0, 0);
            acc2[1][nt] = __builtin_amdgcn_mfma_f32_16x16x32_bf16(a1, b, acc2[1][nt], 0, 0, 0);
        }
    }
    // epilogue: + (u2_b + sc_b), lrelu, store
    #pragma unroll
    for (int nt = 0; nt < 8; ++nt) {
        int col = nt * 16 + nl;
        float bias = u2_b[col] + sc_b[col];
        #pragma unroll
        for (int m = 0; m < 2; ++m) {
            int rowl = (wv * 2 + m) * 16 + quad * 4;
            #pragma unroll
            for (int r = 0; r < 4; ++r) {
                int ptl = gblk * 16 + rowl + r;
                if (ptl < chc)
                    out[(size_t)(c0 + ptl) * COUT + col] = lrelu(acc2[m][nt][r] + bias);
            }
        }
    }
}

extern "C" void kernel_launch(void* const* d_in, const int* in_sizes, int n_in,
                              void* d_out, int out_size, void* d_ws, size_t ws_size,
                              hipStream_t stream) {
    const float* xyz   = (const float*)d_in[0];
    const float* df    = (const float*)d_in[1];
    const int*   nei   = (const int*)d_in[2];
    const float* pe_w1 = (const float*)d_in[3];
    const float* pe_b1 = (const float*)d_in[4];
    const float* pe_w2 = (const float*)d_in[5];
    const float* pe_b2 = (const float*)d_in[6];
    const float* u1_w  = (const float*)d_in[7];
    const float* u1_b  = (const float*)d_in[8];
    const float* wn_w1 = (const float*)d_in[9];
    const float* wn_b1 = (const float*)d_in[10];
    const float* wn_w2 = (const float*)d_in[11];
    const float* wn_b2 = (const float*)d_in[12];
    const float* wn_w3 = (const float*)d_in[13];
    const float* wn_b3 = (const float*)d_in[14];
    const float* lin_w = (const float*)d_in[15];
    const float* lin_b = (const float*)d_in[16];
    const float* u2_w  = (const float*)d_in[17];
    const float* u2_b  = (const float*)d_in[18];
    const float* sc_w  = (const float*)d_in[19];
    const float* sc_b  = (const float*)d_in[20];

    u16* feats  = (u16*)d_ws;
    u16* packB  = (u16*)((char*)d_ws + WS_PACKB);
    u16* packW2 = (u16*)((char*)d_ws + WS_PACKW2);
    u16* agg    = (u16*)((char*)d_ws + WS_AGG);
    float* outp = (float*)d_out;
    float* locout = outp + (size_t)NPTS * COUT;

    // chunk size from ws_size (deterministic -> graph-safe); 2048 B/point
    size_t avail = ws_size > (size_t)WS_AGG ? ws_size - (size_t)WS_AGG : 0;
    long long ch = (long long)(avail / 2048);
    ch &= ~127LL;
    if (ch > NPTS) ch = NPTS;
    if (ch < 128) ch = 128;

    hipLaunchKernelGGL(k_u1, dim3((NPTS * 8 + 255) / 256), dim3(256), 0, stream,
                       df, u1_w, u1_b, feats);
    hipLaunchKernelGGL(k_pack, dim3(65536 / 256), dim3(256), 0, stream, lin_w, packB);
    hipLaunchKernelGGL(k_packW2, dim3(16384 / 256), dim3(256), 0, stream, u2_w, sc_w, packW2);

    for (int c0 = 0; c0 < NPTS; c0 += (int)ch) {
        int chc = NPTS - c0 < (int)ch ? NPTS - c0 : (int)ch;
        hipLaunchKernelGGL(k2_point, dim3(chc), dim3(64), 0, stream,
                           xyz, nei, feats,
                           pe_w1, pe_b1, pe_w2, pe_b2,
                           wn_w1, wn_b1, wn_w2, wn_b2, wn_w3, wn_b3,
                           agg, locout, c0);
        hipLaunchKernelGGL(k3_gemm, dim3((chc + 127) / 128), dim3(256), 0, stream,
                           agg, packB, packW2, lin_b, u2_b, sc_b,
                           df, outp, c0, chc);
    }
}

// Round 5
// 356.864 us; speedup vs baseline: 5.2370x; 1.6335x over previous
//
#include <hip/hip_runtime.h>
#include <stdint.h>

#define NPTS 100000
#define KNEI 16
#define CIN 64
#define CMID 32
#define CONC 64
#define LINI 1024
#define COUT 128

typedef unsigned short u16;
typedef unsigned int u32;
typedef __attribute__((ext_vector_type(8))) short bf16x8;
typedef __attribute__((ext_vector_type(4))) float f32x4;

// ws layout (bytes):
//   [0, 6400000)            feats bf16, N x 32
//   [WS_PACKB, +131072)     packed lin_w bf16 (65536 elems, MFMA B-frag order)
//   [WS_PACKW2, +32768)     packed [u2_w; sc_w] bf16 (16384 elems, B-frag order)
//   [WS_AGG, ...)           agg bf16, ROW-MAJOR [ch][1024]
#define WS_PACKB  6400000
#define WS_PACKW2 (WS_PACKB + 131072)
#define WS_AGG    (WS_PACKW2 + 32768)

__device__ __forceinline__ float lrelu(float x) { return x > 0.f ? x : 0.1f * x; }

__device__ __forceinline__ u32 f2bf(float f) {
    union { float f; u32 u; } v; v.f = f;
    return (v.u + 0x7FFFu + ((v.u >> 16) & 1u)) >> 16;   // RNE
}

// ---- K1a: feats = bf16(dense_feats @ u1_w + u1_b), N x 32 ----
__global__ __launch_bounds__(256) void k_u1(const float* __restrict__ df,
                                            const float* __restrict__ w,
                                            const float* __restrict__ b,
                                            u16* __restrict__ feats) {
    int t = blockIdx.x * 256 + threadIdx.x;
    int n = t >> 3, g = t & 7;
    if (n >= NPTS) return;
    int c = g * 4;
    float4 acc = *(const float4*)(b + c);
    const float* row = df + (size_t)n * CIN;
    #pragma unroll
    for (int j = 0; j < CIN; j += 4) {
        float4 f = *(const float4*)(row + j);
        float4 w0 = *(const float4*)(w + (j + 0) * CMID + c);
        float4 w1 = *(const float4*)(w + (j + 1) * CMID + c);
        float4 w2 = *(const float4*)(w + (j + 2) * CMID + c);
        float4 w3 = *(const float4*)(w + (j + 3) * CMID + c);
        acc.x += f.x * w0.x + f.y * w1.x + f.z * w2.x + f.w * w3.x;
        acc.y += f.x * w0.y + f.y * w1.y + f.z * w2.y + f.w * w3.y;
        acc.z += f.x * w0.z + f.y * w1.z + f.z * w2.z + f.w * w3.z;
        acc.w += f.x * w0.w + f.y * w1.w + f.z * w2.w + f.w * w3.w;
    }
    uint2 o;
    o.x = f2bf(acc.x) | (f2bf(acc.y) << 16);
    o.y = f2bf(acc.z) | (f2bf(acc.w) << 16);
    *(uint2*)(feats + (size_t)n * CMID + c) = o;
}

// ---- K1b: pack lin_w (1024x64 fp32) -> bf16 MFMA B-frag order ----
__global__ __launch_bounds__(256) void k_pack(const float* __restrict__ lin_w,
                                              u16* __restrict__ packB) {
    int t = blockIdx.x * 256 + threadIdx.x;     // 65536 total
    int j = t & 7, ln = (t >> 3) & 63, s = t >> 9;
    int nt = s & 3, kb = s >> 2;
    int k = kb * 32 + (ln >> 4) * 8 + j;
    int n = nt * 16 + (ln & 15);
    packB[t] = (u16)f2bf(lin_w[k * 64 + n]);
}

// ---- K1c: pack W2 = [u2_w; sc_w] (128x128) -> bf16 B-frag order ----
__global__ __launch_bounds__(256) void k_packW2(const float* __restrict__ u2_w,
                                                const float* __restrict__ sc_w,
                                                u16* __restrict__ packW2) {
    int t = blockIdx.x * 256 + threadIdx.x;     // 16384 total
    int j = t & 7, ln = (t >> 3) & 63, s = t >> 9;
    int nt2 = s & 7, kb2 = s >> 3;
    int k = kb2 * 32 + (ln >> 4) * 8 + j;
    int n = nt2 * 16 + (ln & 15);
    float v = (k < 64) ? u2_w[k * COUT + n] : sc_w[(k - 64) * COUT + n];
    packW2[t] = (u16)f2bf(v);
}

// ---- K2: MFMA-based. One wave = 4 points; block = 256 thr = 16 points. ----
__global__ __launch_bounds__(256) void k2_point(
    const float* __restrict__ xyz, const int* __restrict__ nei,
    const u16* __restrict__ feats,
    const float* __restrict__ pe_w1, const float* __restrict__ pe_b1,
    const float* __restrict__ pe_w2, const float* __restrict__ pe_b2,
    const float* __restrict__ wn_w1, const float* __restrict__ wn_b1,
    const float* __restrict__ wn_w2, const float* __restrict__ wn_b2,
    const float* __restrict__ wn_w3, const float* __restrict__ wn_b3,
    u16* __restrict__ agg, float* __restrict__ locout, int c0)
{
    __shared__ float loc_s[4][4][16][3];
    __shared__ int idx_s[4][4][16];                 // neighbor indices (fix: no shfl across exec)
    __shared__ __align__(16) u16 pe_s[4][32][24];   // [pc][k], stride 48B
    __shared__ __align__(16) u16 w_s[4][16][24];    // [o][k],  stride 48B

    const int tid = threadIdx.x, w = tid >> 6, lane = tid & 63;
    const int quad = lane >> 4, nl = lane & 15;
    const int ptBase = c0 + blockIdx.x * 16 + w * 4;

    // ---- step 0: all 4 points' localized coords + indices (lane: it=quad, k=nl) ----
    int pt0 = ptBase + quad;
    int idx0 = nei[pt0 * KNEI + nl];
    idx_s[w][quad][nl] = idx0;
    {
        float cx = xyz[pt0 * 3 + 0], cy = xyz[pt0 * 3 + 1], cz = xyz[pt0 * 3 + 2];
        float lx = xyz[idx0 * 3 + 0] - cx;
        float ly = xyz[idx0 * 3 + 1] - cy;
        float lz = xyz[idx0 * 3 + 2] - cz;
        loc_s[w][quad][nl][0] = lx;
        loc_s[w][quad][nl][1] = ly;
        loc_s[w][quad][nl][2] = lz;
        float* lo = locout + (size_t)(pt0 * KNEI + nl) * 3;
        lo[0] = lx; lo[1] = ly; lo[2] = lz;
    }

    // ---- preload per-lane weights ----
    float w1r0[8], w1r1[8], w1r2[8], b1v[8];
    #pragma unroll
    for (int j = 0; j < 8; ++j) {
        int h = quad * 8 + j;
        w1r0[j] = pe_w1[h]; w1r1[j] = pe_w1[32 + h]; w1r2[j] = pe_w1[64 + h];
        b1v[j] = pe_b1[h];
    }
    bf16x8 w2t[2];
    #pragma unroll
    for (int ct = 0; ct < 2; ++ct)
        #pragma unroll
        for (int j = 0; j < 8; ++j)
            w2t[ct][j] = (short)f2bf(pe_w2[(quad * 8 + j) * 32 + nl + 16 * ct]);
    float b2v[2][4];
    #pragma unroll
    for (int ct = 0; ct < 2; ++ct)
        #pragma unroll
        for (int r = 0; r < 4; ++r)
            b2v[ct][r] = pe_b2[16 * ct + quad * 4 + r];
    float wn3v[8][4], wnb3v[4];
    #pragma unroll
    for (int h = 0; h < 8; ++h)
        #pragma unroll
        for (int r = 0; r < 4; ++r)
            wn3v[h][r] = wn_w3[h * 16 + quad * 4 + r];
    #pragma unroll
    for (int r = 0; r < 4; ++r) wnb3v[r] = wn_b3[quad * 4 + r];

    __syncthreads();

    const f32x4 zacc = {0.f, 0.f, 0.f, 0.f};

    for (int p = 0; p < 4; ++p) {
        int pt = ptBase + p;

        // ---- feats gather straight into B-frag (quads 0,1; 2,3 zero) ----
        bf16x8 featf0 = 0, featf1 = 0;
        if (quad < 2) {
            #pragma unroll
            for (int j = 0; j < 8; ++j) {
                int idk = idx_s[w][p][quad * 8 + j];
                featf0[j] = (short)feats[(size_t)idk * CMID + nl];
                featf1[j] = (short)feats[(size_t)idk * CMID + nl + 16];
            }
        }

        float lx = loc_s[w][p][nl][0];
        float ly = loc_s[w][p][nl][1];
        float lz = loc_s[w][p][nl][2];

        // ---- B1: ph in B-frag layout (h=quad*8+j, k_nei=nl) ----
        bf16x8 phf;
        #pragma unroll
        for (int j = 0; j < 8; ++j) {
            float v = lrelu(b1v[j] + lx * w1r0[j] + ly * w1r1[j] + lz * w1r2[j]);
            phf[j] = (short)f2bf(v);
        }

        // ---- B2: pe^T = w2^T @ ph  (D[c][k_nei]) : 2 MFMAs ----
        f32x4 pe0 = __builtin_amdgcn_mfma_f32_16x16x32_bf16(w2t[0], phf, zacc, 0, 0, 0);
        f32x4 pe1 = __builtin_amdgcn_mfma_f32_16x16x32_bf16(w2t[1], phf, zacc, 0, 0, 0);

        // epilogue: bias+lrelu, transpose via LDS -> pe_s[pc][k]
        #pragma unroll
        for (int r = 0; r < 4; ++r) {
            pe_s[w][quad * 4 + r][nl]      = (u16)f2bf(lrelu(pe0[r] + b2v[0][r]));
            pe_s[w][16 + quad * 4 + r][nl] = (u16)f2bf(lrelu(pe1[r] + b2v[1][r]));
        }

        // ---- WeightNet (k=nl; lane computes o=quad*4+r) ----
        {
            float h1[8], h2[8];
            #pragma unroll
            for (int h = 0; h < 8; ++h)
                h1[h] = lrelu(wn_b1[h] + lx * wn_w1[h] + ly * wn_w1[8 + h] + lz * wn_w1[16 + h]);
            #pragma unroll
            for (int o2 = 0; o2 < 8; ++o2) {
                float a = wn_b2[o2];
                #pragma unroll
                for (int h = 0; h < 8; ++h) a += h1[h] * wn_w2[h * 8 + o2];
                h2[o2] = a;
            }
            #pragma unroll
            for (int r = 0; r < 4; ++r) {
                float a = wnb3v[r];
                #pragma unroll
                for (int h = 0; h < 8; ++h) a += h2[h] * wn3v[h][r];
                w_s[w][quad * 4 + r][nl] = (u16)f2bf(lrelu(a));
            }
        }
        __syncthreads();

        // ---- read frags: wA (A: o=nl, k=quad*8+j), peB (B: k=quad*8+j, c=nl) ----
        bf16x8 wA = 0, peB0 = 0, peB1 = 0;
        if (quad < 2) {
            wA   = *(const bf16x8*)&w_s[w][nl][quad * 8];
            peB0 = *(const bf16x8*)&pe_s[w][nl][quad * 8];
            peB1 = *(const bf16x8*)&pe_s[w][nl + 16][quad * 8];
        }

        // ---- Stage C: D[o][c] = w^T @ nf, 4 c-tiles, K=16 (padded to 32) ----
        f32x4 c0a = __builtin_amdgcn_mfma_f32_16x16x32_bf16(wA, featf0, zacc, 0, 0, 0);
        f32x4 c1a = __builtin_amdgcn_mfma_f32_16x16x32_bf16(wA, featf1, zacc, 0, 0, 0);
        f32x4 c2a = __builtin_amdgcn_mfma_f32_16x16x32_bf16(wA, peB0, zacc, 0, 0, 0);
        f32x4 c3a = __builtin_amdgcn_mfma_f32_16x16x32_bf16(wA, peB1, zacc, 0, 0, 0);

        // ---- store agg row-major, coalesced 8B chunks (e = c*16+o) ----
        {
            u16* arow = agg + (size_t)(pt - c0) * LINI;
            f32x4 cc[4] = {c0a, c1a, c2a, c3a};
            #pragma unroll
            for (int ct = 0; ct < 4; ++ct) {
                int e = (nl + 16 * ct) * 16 + quad * 4;
                uint2 o;
                o.x = f2bf(cc[ct][0]) | (f2bf(cc[ct][1]) << 16);
                o.y = f2bf(cc[ct][2]) | (f2bf(cc[ct][3]) << 16);
                *(uint2*)(arow + e) = o;
            }
        }
        __syncthreads();
    }
}

// ---- K3: GEMM1 (agg row-major @ lin_w, MFMA) -> x; GEMM2 ([x|df] @ W2) -> out
__global__ __launch_bounds__(256) void k3_gemm(
    const u16* __restrict__ agg, const u16* __restrict__ packB,
    const u16* __restrict__ packW2,
    const float* __restrict__ lin_b,
    const float* __restrict__ u2_b, const float* __restrict__ sc_b,
    const float* __restrict__ df, float* __restrict__ out,
    int c0, int chc)
{
    __shared__ __align__(16) char lds[65536];
    u16* regA = (u16*)lds;           // [0,32K): GEMM1 B superchunk (16K) then W2 (32K)
    u16* xd   = (u16*)(lds + 32768); // [32K,64K): [x|df] in A-frag order [g8][kb2][64][8]

    const int tid = threadIdx.x, wv = tid >> 6, lane = tid & 63;
    const int quad = lane >> 4, nl = lane & 15;
    const int gblk = blockIdx.x * 8;

    // row-major A pointers (two 16-pt m-tiles per wave)
    int r0 = blockIdx.x * 128 + wv * 32 + nl;
    int r1 = r0 + 16;
    int r0c = r0 < chc ? r0 : chc - 1;
    int r1c = r1 < chc ? r1 : chc - 1;
    const u16* a0p = agg + (size_t)r0c * LINI + quad * 8;
    const u16* a1p = agg + (size_t)r1c * LINI + quad * 8;

    f32x4 acc[2][4];
    #pragma unroll
    for (int m = 0; m < 2; ++m)
        #pragma unroll
        for (int nt = 0; nt < 4; ++nt) acc[m][nt] = (f32x4){0.f, 0.f, 0.f, 0.f};

    // prefetch B superchunk 0 to regs, A kb=0
    uint4 st0, st1, st2, st3;
    {
        const uint4* src = (const uint4*)packB + tid;
        st0 = src[0]; st1 = src[256]; st2 = src[512]; st3 = src[768];
    }
    bf16x8 a0n = *(const bf16x8*)a0p;
    bf16x8 a1n = *(const bf16x8*)a1p;

    for (int sc = 0; sc < 8; ++sc) {
        __syncthreads();
        uint4* bb = (uint4*)regA;
        bb[tid] = st0; bb[tid + 256] = st1; bb[tid + 512] = st2; bb[tid + 768] = st3;
        __syncthreads();
        if (sc < 7) {
            const uint4* src = (const uint4*)(packB + (size_t)(sc + 1) * 8192) + tid;
            st0 = src[0]; st1 = src[256]; st2 = src[512]; st3 = src[768];
        }
        #pragma unroll
        for (int kbL = 0; kbL < 4; ++kbL) {
            int kb = sc * 4 + kbL;
            bf16x8 a0 = a0n, a1 = a1n;
            int kn = kb < 31 ? kb + 1 : 31;
            a0n = *(const bf16x8*)(a0p + (size_t)kn * 32);
            a1n = *(const bf16x8*)(a1p + (size_t)kn * 32);
            const u16* bp = regA + kbL * 2048 + lane * 8;
            bf16x8 b0 = *(const bf16x8*)(bp);
            bf16x8 b1 = *(const bf16x8*)(bp + 512);
            bf16x8 b2 = *(const bf16x8*)(bp + 1024);
            bf16x8 b3 = *(const bf16x8*)(bp + 1536);
            acc[0][0] = __builtin_amdgcn_mfma_f32_16x16x32_bf16(a0, b0, acc[0][0], 0, 0, 0);
            acc[1][0] = __builtin_amdgcn_mfma_f32_16x16x32_bf16(a1, b0, acc[1][0], 0, 0, 0);
            acc[0][1] = __builtin_amdgcn_mfma_f32_16x16x32_bf16(a0, b1, acc[0][1], 0, 0, 0);
            acc[1][1] = __builtin_amdgcn_mfma_f32_16x16x32_bf16(a1, b1, acc[1][1], 0, 0, 0);
            acc[0][2] = __builtin_amdgcn_mfma_f32_16x16x32_bf16(a0, b2, acc[0][2], 0, 0, 0);
            acc[1][2] = __builtin_amdgcn_mfma_f32_16x16x32_bf16(a1, b2, acc[1][2], 0, 0, 0);
            acc[0][3] = __builtin_amdgcn_mfma_f32_16x16x32_bf16(a0, b3, acc[0][3], 0, 0, 0);
            acc[1][3] = __builtin_amdgcn_mfma_f32_16x16x32_bf16(a1, b3, acc[1][3], 0, 0, 0);
        }
    }

    __syncthreads();   // all GEMM1 LDS reads done

    // stage W2 into regA (32 KB)
    {
        const uint4* src = (const uint4*)packW2;
        uint4* dst = (uint4*)regA;
        #pragma unroll
        for (int i = 0; i < 8; ++i) dst[i * 256 + tid] = src[i * 256 + tid];
    }
    // x -> xd (cols 0..63), bf16, A-frag order
    #pragma unroll
    for (int m = 0; m < 2; ++m) {
        int g8 = wv * 2 + m;
        #pragma unroll
        for (int nt = 0; nt < 4; ++nt) {
            int colk = nt * 16 + nl;
            float lb = lin_b[colk];
            int kb2 = colk >> 5, q2 = (colk >> 3) & 3, j2 = colk & 7;
            #pragma unroll
            for (int r = 0; r < 4; ++r) {
                int row16 = quad * 4 + r;
                float v = lrelu(acc[m][nt][r] + lb);
                xd[((g8 * 4 + kb2) * 64 + q2 * 16 + row16) * 8 + j2] = (u16)f2bf(v);
            }
        }
    }
    // df -> xd (cols 64..127)
    {
        int row = tid >> 1, half = tid & 1;
        int ptl = gblk * 16 + row;
        int ptc = ptl < chc ? (c0 + ptl) : c0;
        int g8 = row >> 4, row16 = row & 15;
        const float* dfr = df + (size_t)ptc * CIN + half * 32;
        #pragma unroll
        for (int jj = 0; jj < 32; jj += 8) {
            float4 f0 = *(const float4*)(dfr + jj);
            float4 f1 = *(const float4*)(dfr + jj + 4);
            int colk = 64 + half * 32 + jj;
            int kb2 = colk >> 5, q2 = (colk >> 3) & 3;
            uint4 o;
            o.x = f2bf(f0.x) | (f2bf(f0.y) << 16);
            o.y = f2bf(f0.z) | (f2bf(f0.w) << 16);
            o.z = f2bf(f1.x) | (f2bf(f1.y) << 16);
            o.w = f2bf(f1.z) | (f2bf(f1.w) << 16);
            *(uint4*)(xd + ((g8 * 4 + kb2) * 64 + q2 * 16 + row16) * 8) = o;
        }
    }
    __syncthreads();

    // GEMM2: [x|df] (128x128) @ W2 (128x128)
    f32x4 acc2[2][8];
    #pragma unroll
    for (int m = 0; m < 2; ++m)
        #pragma unroll
        for (int nt = 0; nt < 8; ++nt) acc2[m][nt] = (f32x4){0.f, 0.f, 0.f, 0.f};
    #pragma unroll
    for (int kb2 = 0; kb2 < 4; ++kb2) {
        bf16x8 a0 = *(const bf16x8*)(xd + ((size_t)((wv * 2 + 0) * 4 + kb2)) * 512 + lane * 8);
        bf16x8 a1 = *(const bf16x8*)(xd + ((size_t)((wv * 2 + 1) * 4 + kb2)) * 512 + lane * 8);
        #pragma unroll
        for (int nt = 0; nt < 8; ++nt) {
            bf16x8 b = *(const bf16x8*)(regA + (kb2 * 8 + nt) * 512 + lane * 8);
            acc2[0][nt] = __builtin_amdgcn_mfma_f32_16x16x32_bf16(a0, b, acc2[0][nt], 0, 0, 0);
            acc2[1][nt] = __builtin_amdgcn_mfma_f32_16x16x32_bf16(a1, b, acc2[1][nt], 0, 0, 0);
        }
    }
    // epilogue: + (u2_b + sc_b), lrelu, store
    #pragma unroll
    for (int nt = 0; nt < 8; ++nt) {
        int col = nt * 16 + nl;
        float bias = u2_b[col] + sc_b[col];
        #pragma unroll
        for (int m = 0; m < 2; ++m) {
            int rowl = (wv * 2 + m) * 16 + quad * 4;
            #pragma unroll
            for (int r = 0; r < 4; ++r) {
                int ptl = gblk * 16 + rowl + r;
                if (ptl < chc)
                    out[(size_t)(c0 + ptl) * COUT + col] = lrelu(acc2[m][nt][r] + bias);
            }
        }
    }
}

extern "C" void kernel_launch(void* const* d_in, const int* in_sizes, int n_in,
                              void* d_out, int out_size, void* d_ws, size_t ws_size,
                              hipStream_t stream) {
    const float* xyz   = (const float*)d_in[0];
    const float* df    = (const float*)d_in[1];
    const int*   nei   = (const int*)d_in[2];
    const float* pe_w1 = (const float*)d_in[3];
    const float* pe_b1 = (const float*)d_in[4];
    const float* pe_w2 = (const float*)d_in[5];
    const float* pe_b2 = (const float*)d_in[6];
    const float* u1_w  = (const float*)d_in[7];
    const float* u1_b  = (const float*)d_in[8];
    const float* wn_w1 = (const float*)d_in[9];
    const float* wn_b1 = (const float*)d_in[10];
    const float* wn_w2 = (const float*)d_in[11];
    const float* wn_b2 = (const float*)d_in[12];
    const float* wn_w3 = (const float*)d_in[13];
    const float* wn_b3 = (const float*)d_in[14];
    const float* lin_w = (const float*)d_in[15];
    const float* lin_b = (const float*)d_in[16];
    const float* u2_w  = (const float*)d_in[17];
    const float* u2_b  = (const float*)d_in[18];
    const float* sc_w  = (const float*)d_in[19];
    const float* sc_b  = (const float*)d_in[20];

    u16* feats  = (u16*)d_ws;
    u16* packB  = (u16*)((char*)d_ws + WS_PACKB);
    u16* packW2 = (u16*)((char*)d_ws + WS_PACKW2);
    u16* agg    = (u16*)((char*)d_ws + WS_AGG);
    float* outp = (float*)d_out;
    float* locout = outp + (size_t)NPTS * COUT;

    // chunk size from ws_size (deterministic -> graph-safe); 2048 B/point
    size_t avail = ws_size > (size_t)WS_AGG ? ws_size - (size_t)WS_AGG : 0;
    long long ch = (long long)(avail / 2048);
    ch &= ~127LL;
    if (ch > NPTS) ch = NPTS;
    if (ch < 128) ch = 128;

    hipLaunchKernelGGL(k_u1, dim3((NPTS * 8 + 255) / 256), dim3(256), 0, stream,
                       df, u1_w, u1_b, feats);
    hipLaunchKernelGGL(k_pack, dim3(65536 / 256), dim3(256), 0, stream, lin_w, packB);
    hipLaunchKernelGGL(k_packW2, dim3(16384 / 256), dim3(256), 0, stream, u2_w, sc_w, packW2);

    for (int c0 = 0; c0 < NPTS; c0 += (int)ch) {
        int chc = NPTS - c0 < (int)ch ? NPTS - c0 : (int)ch;   // multiple of 16
        hipLaunchKernelGGL(k2_point, dim3(chc / 16), dim3(256), 0, stream,
                           xyz, nei, feats,
                           pe_w1, pe_b1, pe_w2, pe_b2,
                           wn_w1, wn_b1, wn_w2, wn_b2, wn_w3, wn_b3,
                           agg, locout, c0);
        hipLaunchKernelGGL(k3_gemm, dim3((chc + 127) / 128), dim3(256), 0, stream,
                           agg, packB, packW2, lin_b, u2_b, sc_b,
                           df, outp, c0, chc);
    }
}

// Round 6
// 310.521 us; speedup vs baseline: 6.0186x; 1.1492x over previous
//
#include <hip/hip_runtime.h>
#include <stdint.h>

#define NPTS 100000
#define KNEI 16
#define CIN 64
#define CMID 32
#define CONC 64
#define LINI 1024
#define COUT 128
#define APITCH 1040   // u16 per aggL row (16-u16 pad)

typedef unsigned short u16;
typedef unsigned int u32;
typedef __attribute__((ext_vector_type(8))) short bf16x8;
typedef __attribute__((ext_vector_type(4))) float f32x4;

// ws layout (bytes):
//   [0, 6400000)            feats bf16, N x 32
//   [WS_PACKB, +131072)     packed lin_w bf16 (65536 elems, MFMA B-frag order)
//   [WS_PACKW2, +32768)     packed [u2_w; sc_w] bf16 (16384 elems, B-frag order)
#define WS_PACKB  6400000
#define WS_PACKW2 (WS_PACKB + 131072)

__device__ __forceinline__ float lrelu(float x) { return x > 0.f ? x : 0.1f * x; }

__device__ __forceinline__ u32 f2bf(float f) {
    union { float f; u32 u; } v; v.f = f;
    return (v.u + 0x7FFFu + ((v.u >> 16) & 1u)) >> 16;   // RNE
}

// ---- K1a: feats = bf16(dense_feats @ u1_w + u1_b), N x 32 ----
__global__ __launch_bounds__(256) void k_u1(const float* __restrict__ df,
                                            const float* __restrict__ w,
                                            const float* __restrict__ b,
                                            u16* __restrict__ feats) {
    int t = blockIdx.x * 256 + threadIdx.x;
    int n = t >> 3, g = t & 7;
    if (n >= NPTS) return;
    int c = g * 4;
    float4 acc = *(const float4*)(b + c);
    const float* row = df + (size_t)n * CIN;
    #pragma unroll
    for (int j = 0; j < CIN; j += 4) {
        float4 f = *(const float4*)(row + j);
        float4 w0 = *(const float4*)(w + (j + 0) * CMID + c);
        float4 w1 = *(const float4*)(w + (j + 1) * CMID + c);
        float4 w2 = *(const float4*)(w + (j + 2) * CMID + c);
        float4 w3 = *(const float4*)(w + (j + 3) * CMID + c);
        acc.x += f.x * w0.x + f.y * w1.x + f.z * w2.x + f.w * w3.x;
        acc.y += f.x * w0.y + f.y * w1.y + f.z * w2.y + f.w * w3.y;
        acc.z += f.x * w0.z + f.y * w1.z + f.z * w2.z + f.w * w3.z;
        acc.w += f.x * w0.w + f.y * w1.w + f.z * w2.w + f.w * w3.w;
    }
    uint2 o;
    o.x = f2bf(acc.x) | (f2bf(acc.y) << 16);
    o.y = f2bf(acc.z) | (f2bf(acc.w) << 16);
    *(uint2*)(feats + (size_t)n * CMID + c) = o;
}

// ---- K1b: pack lin_w (1024x64 fp32) -> bf16 MFMA B-frag order ----
__global__ __launch_bounds__(256) void k_pack(const float* __restrict__ lin_w,
                                              u16* __restrict__ packB) {
    int t = blockIdx.x * 256 + threadIdx.x;     // 65536 total
    int j = t & 7, ln = (t >> 3) & 63, s = t >> 9;
    int nt = s & 3, kb = s >> 2;
    int k = kb * 32 + (ln >> 4) * 8 + j;
    int n = nt * 16 + (ln & 15);
    packB[t] = (u16)f2bf(lin_w[k * 64 + n]);
}

// ---- K1c: pack W2 = [u2_w; sc_w] (128x128) -> bf16 B-frag order ----
__global__ __launch_bounds__(256) void k_packW2(const float* __restrict__ u2_w,
                                                const float* __restrict__ sc_w,
                                                u16* __restrict__ packW2) {
    int t = blockIdx.x * 256 + threadIdx.x;     // 16384 total
    int j = t & 7, ln = (t >> 3) & 63, s = t >> 9;
    int nt2 = s & 7, kb2 = s >> 3;
    int k = kb2 * 32 + (ln >> 4) * 8 + j;
    int n = nt2 * 16 + (ln & 15);
    float v = (k < 64) ? u2_w[k * COUT + n] : sc_w[(k - 64) * COUT + n];
    packW2[t] = (u16)f2bf(v);
}

// ---- Fused: gather/PE/WN/einsum (phase 1) + GEMM1 + GEMM2 (phase 2). ----
// Block = 256 threads = 16 points; one wave handles 4 points in phase 1.
__global__ __launch_bounds__(256) void k_fused(
    const float* __restrict__ xyz, const int* __restrict__ nei,
    const u16* __restrict__ feats,
    const float* __restrict__ pe_w1, const float* __restrict__ pe_b1,
    const float* __restrict__ pe_w2, const float* __restrict__ pe_b2,
    const float* __restrict__ wn_w1, const float* __restrict__ wn_b1,
    const float* __restrict__ wn_w2, const float* __restrict__ wn_b2,
    const float* __restrict__ wn_w3, const float* __restrict__ wn_b3,
    const u16* __restrict__ packB, const u16* __restrict__ packW2,
    const float* __restrict__ lin_b,
    const float* __restrict__ u2_b, const float* __restrict__ sc_b,
    const float* __restrict__ df, float* __restrict__ out,
    float* __restrict__ locout)
{
    __shared__ __align__(16) u16 aggL[16 * APITCH];   // 33,280 B (granule-swizzled rows)
    __shared__ float loc_s[4][4][16][3];
    __shared__ int   idx_s[4][4][16];
    __shared__ __align__(16) u16 pe_s[4][32][24];
    __shared__ __align__(16) u16 w_s[4][16][24];
    __shared__ __align__(16) u16 xd[4 * 64 * 8];      // [x|df] A-frag order, 4 KB

    const int tid = threadIdx.x, wv = tid >> 6, lane = tid & 63;
    const int quad = lane >> 4, nl = lane & 15;
    const int p0 = blockIdx.x * 16;
    const int ptBase = p0 + wv * 4;

    // ---- phase 1, step 0: coords + indices (lane: point=quad, k=nl) ----
    int pt0 = ptBase + quad;
    int idx0 = nei[pt0 * KNEI + nl];
    idx_s[wv][quad][nl] = idx0;
    {
        float cx = xyz[pt0 * 3 + 0], cy = xyz[pt0 * 3 + 1], cz = xyz[pt0 * 3 + 2];
        float lx = xyz[idx0 * 3 + 0] - cx;
        float ly = xyz[idx0 * 3 + 1] - cy;
        float lz = xyz[idx0 * 3 + 2] - cz;
        loc_s[wv][quad][nl][0] = lx;
        loc_s[wv][quad][nl][1] = ly;
        loc_s[wv][quad][nl][2] = lz;
        float* lo = locout + (size_t)(pt0 * KNEI + nl) * 3;
        lo[0] = lx; lo[1] = ly; lo[2] = lz;
    }

    // ---- preload per-lane weights ----
    float w1r0[8], w1r1[8], w1r2[8], b1v[8];
    #pragma unroll
    for (int j = 0; j < 8; ++j) {
        int h = quad * 8 + j;
        w1r0[j] = pe_w1[h]; w1r1[j] = pe_w1[32 + h]; w1r2[j] = pe_w1[64 + h];
        b1v[j] = pe_b1[h];
    }
    bf16x8 w2t[2];
    #pragma unroll
    for (int ct = 0; ct < 2; ++ct)
        #pragma unroll
        for (int j = 0; j < 8; ++j)
            w2t[ct][j] = (short)f2bf(pe_w2[(quad * 8 + j) * 32 + nl + 16 * ct]);
    float b2v[2][4];
    #pragma unroll
    for (int ct = 0; ct < 2; ++ct)
        #pragma unroll
        for (int r = 0; r < 4; ++r)
            b2v[ct][r] = pe_b2[16 * ct + quad * 4 + r];
    float wn3v[8][4], wnb3v[4];
    #pragma unroll
    for (int h = 0; h < 8; ++h)
        #pragma unroll
        for (int r = 0; r < 4; ++r)
            wn3v[h][r] = wn_w3[h * 16 + quad * 4 + r];
    #pragma unroll
    for (int r = 0; r < 4; ++r) wnb3v[r] = wn_b3[quad * 4 + r];

    __syncthreads();

    const f32x4 zacc = {0.f, 0.f, 0.f, 0.f};

    for (int p = 0; p < 4; ++p) {
        const int m = wv * 4 + p;   // block-local point row

        // ---- feats gather straight into B-frag (quads 0,1; 2,3 zero) ----
        bf16x8 featf0 = 0, featf1 = 0;
        if (quad < 2) {
            #pragma unroll
            for (int j = 0; j < 8; ++j) {
                int idk = idx_s[wv][p][quad * 8 + j];
                featf0[j] = (short)feats[(size_t)idk * CMID + nl];
                featf1[j] = (short)feats[(size_t)idk * CMID + nl + 16];
            }
        }

        float lx = loc_s[wv][p][nl][0];
        float ly = loc_s[wv][p][nl][1];
        float lz = loc_s[wv][p][nl][2];

        // ---- B1: ph in B-frag layout (h=quad*8+j, k_nei=nl) ----
        bf16x8 phf;
        #pragma unroll
        for (int j = 0; j < 8; ++j) {
            float v = lrelu(b1v[j] + lx * w1r0[j] + ly * w1r1[j] + lz * w1r2[j]);
            phf[j] = (short)f2bf(v);
        }

        // ---- B2: pe^T = w2^T @ ph : 2 MFMAs ----
        f32x4 pe0 = __builtin_amdgcn_mfma_f32_16x16x32_bf16(w2t[0], phf, zacc, 0, 0, 0);
        f32x4 pe1 = __builtin_amdgcn_mfma_f32_16x16x32_bf16(w2t[1], phf, zacc, 0, 0, 0);

        #pragma unroll
        for (int r = 0; r < 4; ++r) {
            pe_s[wv][quad * 4 + r][nl]      = (u16)f2bf(lrelu(pe0[r] + b2v[0][r]));
            pe_s[wv][16 + quad * 4 + r][nl] = (u16)f2bf(lrelu(pe1[r] + b2v[1][r]));
        }

        // ---- WeightNet (k=nl; lane computes o=quad*4+r) ----
        {
            float h1[8], h2[8];
            #pragma unroll
            for (int h = 0; h < 8; ++h)
                h1[h] = lrelu(wn_b1[h] + lx * wn_w1[h] + ly * wn_w1[8 + h] + lz * wn_w1[16 + h]);
            #pragma unroll
            for (int o2 = 0; o2 < 8; ++o2) {
                float a = wn_b2[o2];
                #pragma unroll
                for (int h = 0; h < 8; ++h) a += h1[h] * wn_w2[h * 8 + o2];
                h2[o2] = a;
            }
            #pragma unroll
            for (int r = 0; r < 4; ++r) {
                float a = wnb3v[r];
                #pragma unroll
                for (int h = 0; h < 8; ++h) a += h2[h] * wn3v[h][r];
                w_s[wv][quad * 4 + r][nl] = (u16)f2bf(lrelu(a));
            }
        }
        __syncthreads();

        // ---- read frags: wA (A: o=nl, k=quad*8+j), peB (B: k, c=nl) ----
        bf16x8 wA = 0, peB0 = 0, peB1 = 0;
        if (quad < 2) {
            wA   = *(const bf16x8*)&w_s[wv][nl][quad * 8];
            peB0 = *(const bf16x8*)&pe_s[wv][nl][quad * 8];
            peB1 = *(const bf16x8*)&pe_s[wv][nl + 16][quad * 8];
        }

        // ---- einsum: D[o][c] = w^T @ nf, 4 c-tiles, K=16 (padded) ----
        f32x4 c0a = __builtin_amdgcn_mfma_f32_16x16x32_bf16(wA, featf0, zacc, 0, 0, 0);
        f32x4 c1a = __builtin_amdgcn_mfma_f32_16x16x32_bf16(wA, featf1, zacc, 0, 0, 0);
        f32x4 c2a = __builtin_amdgcn_mfma_f32_16x16x32_bf16(wA, peB0, zacc, 0, 0, 0);
        f32x4 c3a = __builtin_amdgcn_mfma_f32_16x16x32_bf16(wA, peB1, zacc, 0, 0, 0);

        // ---- store agg row into LDS (granule-XOR swizzle per row) ----
        {
            u16* arow = aggL + m * APITCH;
            f32x4 cc[4] = {c0a, c1a, c2a, c3a};
            #pragma unroll
            for (int ct = 0; ct < 4; ++ct) {
                int e0 = (nl + 16 * ct) * 16 + quad * 4;
                int g = e0 >> 3, off = e0 & 7;
                int e = ((g ^ (m & 3)) << 3) + off;
                uint2 o;
                o.x = f2bf(cc[ct][0]) | (f2bf(cc[ct][1]) << 16);
                o.y = f2bf(cc[ct][2]) | (f2bf(cc[ct][3]) << 16);
                *(uint2*)(arow + e) = o;
            }
        }
        __syncthreads();
    }

    // ================= phase 2 =================
    // GEMM1: x[16][64] = lrelu(agg @ lin_w + lin_b); wave wv owns n-tile nt=wv.
    const int nt = wv;
    {
        const u16* bp = packB + nt * 512 + lane * 8;
        const u16* arow = aggL + nl * APITCH;
        const int sw = nl & 3;
        f32x4 accA = zacc, accB = zacc;
        #pragma unroll
        for (int kk = 0; kk < 16; ++kk) {
            int kbA = 2 * kk, kbB = 2 * kk + 1;
            int gA = (4 * kbA + quad) ^ sw;
            int gB = (4 * kbB + quad) ^ sw;
            bf16x8 aA = *(const bf16x8*)(arow + gA * 8);
            bf16x8 aB = *(const bf16x8*)(arow + gB * 8);
            bf16x8 bA = *(const bf16x8*)(bp + kbA * 2048);
            bf16x8 bB = *(const bf16x8*)(bp + kbB * 2048);
            accA = __builtin_amdgcn_mfma_f32_16x16x32_bf16(aA, bA, accA, 0, 0, 0);
            accB = __builtin_amdgcn_mfma_f32_16x16x32_bf16(aB, bB, accB, 0, 0, 0);
        }
        // epilogue: lane holds x[m=quad*4+r][col=nt*16+nl] -> xd A-frag
        int col = nt * 16 + nl;
        float lb = lin_b[col];
        int kb2 = col >> 5, q2 = (col >> 3) & 3, j2 = col & 7;
        #pragma unroll
        for (int r = 0; r < 4; ++r) {
            int m = quad * 4 + r;
            float v = lrelu(accA[r] + accB[r] + lb);
            xd[(kb2 * 64 + q2 * 16 + m) * 8 + j2] = (u16)f2bf(v);
        }
    }
    // df -> xd (cols 64..127)
    if (tid < 128) {
        int m = tid >> 3, cg = tid & 7;
        int colk = 64 + cg * 8;
        const float* dfr = df + (size_t)(p0 + m) * CIN + cg * 8;
        float4 f0 = *(const float4*)(dfr);
        float4 f1 = *(const float4*)(dfr + 4);
        int kb2 = colk >> 5, q2 = (colk >> 3) & 3;
        uint4 o;
        o.x = f2bf(f0.x) | (f2bf(f0.y) << 16);
        o.y = f2bf(f0.z) | (f2bf(f0.w) << 16);
        o.z = f2bf(f1.x) | (f2bf(f1.y) << 16);
        o.w = f2bf(f1.z) | (f2bf(f1.w) << 16);
        *(uint4*)(xd + (kb2 * 64 + q2 * 16 + m) * 8) = o;
    }
    __syncthreads();

    // GEMM2: out[16][128] = lrelu([x|df] @ W2 + u2_b + sc_b); wave owns 2 n-tiles
    {
        f32x4 acc20 = zacc, acc21 = zacc;
        #pragma unroll
        for (int kb = 0; kb < 4; ++kb) {
            bf16x8 a = *(const bf16x8*)(xd + (kb * 64 + lane) * 8);
            bf16x8 b0 = *(const bf16x8*)(packW2 + (size_t)(kb * 8 + wv * 2 + 0) * 512 + lane * 8);
            bf16x8 b1 = *(const bf16x8*)(packW2 + (size_t)(kb * 8 + wv * 2 + 1) * 512 + lane * 8);
            acc20 = __builtin_amdgcn_mfma_f32_16x16x32_bf16(a, b0, acc20, 0, 0, 0);
            acc21 = __builtin_amdgcn_mfma_f32_16x16x32_bf16(a, b1, acc21, 0, 0, 0);
        }
        #pragma unroll
        for (int t = 0; t < 2; ++t) {
            f32x4 ac = t ? acc21 : acc20;
            int colo = (wv * 2 + t) * 16 + nl;
            float bias = u2_b[colo] + sc_b[colo];
            #pragma unroll
            for (int r = 0; r < 4; ++r) {
                int m = quad * 4 + r;
                out[(size_t)(p0 + m) * COUT + colo] = lrelu(ac[r] + bias);
            }
        }
    }
}

extern "C" void kernel_launch(void* const* d_in, const int* in_sizes, int n_in,
                              void* d_out, int out_size, void* d_ws, size_t ws_size,
                              hipStream_t stream) {
    const float* xyz   = (const float*)d_in[0];
    const float* df    = (const float*)d_in[1];
    const int*   nei   = (const int*)d_in[2];
    const float* pe_w1 = (const float*)d_in[3];
    const float* pe_b1 = (const float*)d_in[4];
    const float* pe_w2 = (const float*)d_in[5];
    const float* pe_b2 = (const float*)d_in[6];
    const float* u1_w  = (const float*)d_in[7];
    const float* u1_b  = (const float*)d_in[8];
    const float* wn_w1 = (const float*)d_in[9];
    const float* wn_b1 = (const float*)d_in[10];
    const float* wn_w2 = (const float*)d_in[11];
    const float* wn_b2 = (const float*)d_in[12];
    const float* wn_w3 = (const float*)d_in[13];
    const float* wn_b3 = (const float*)d_in[14];
    const float* lin_w = (const float*)d_in[15];
    const float* lin_b = (const float*)d_in[16];
    const float* u2_w  = (const float*)d_in[17];
    const float* u2_b  = (const float*)d_in[18];
    const float* sc_w  = (const float*)d_in[19];
    const float* sc_b  = (const float*)d_in[20];

    u16* feats  = (u16*)d_ws;
    u16* packB  = (u16*)((char*)d_ws + WS_PACKB);
    u16* packW2 = (u16*)((char*)d_ws + WS_PACKW2);
    float* outp = (float*)d_out;
    float* locout = outp + (size_t)NPTS * COUT;

    hipLaunchKernelGGL(k_u1, dim3((NPTS * 8 + 255) / 256), dim3(256), 0, stream,
                       df, u1_w, u1_b, feats);
    hipLaunchKernelGGL(k_pack, dim3(65536 / 256), dim3(256), 0, stream, lin_w, packB);
    hipLaunchKernelGGL(k_packW2, dim3(16384 / 256), dim3(256), 0, stream, u2_w, sc_w, packW2);

    hipLaunchKernelGGL(k_fused, dim3(NPTS / 16), dim3(256), 0, stream,
                       xyz, nei, feats,
                       pe_w1, pe_b1, pe_w2, pe_b2,
                       wn_w1, wn_b1, wn_w2, wn_b2, wn_w3, wn_b3,
                       packB, packW2, lin_b, u2_b, sc_b,
                       df, outp, locout);
}

// Round 7
// 294.312 us; speedup vs baseline: 6.3500x; 1.0551x over previous
//
#include <hip/hip_runtime.h>
#include <stdint.h>

#define NPTS 100000
#define KNEI 16
#define CIN 64
#define CMID 32
#define CONC 64
#define LINI 1024
#define COUT 128
#define APITCH 1032   // u16 per aggL row: 516 words -> 129 bank-groups (odd mod 8)

typedef unsigned short u16;
typedef unsigned int u32;
typedef __attribute__((ext_vector_type(8))) short bf16x8;
typedef __attribute__((ext_vector_type(4))) float f32x4;

// ws layout (bytes):
//   [0, 6400000)            feats bf16, N x 32
//   [WS_PACKB, +131072)     packed lin_w bf16 (65536 elems, MFMA B-frag order)
//   [WS_PACKW2, +32768)     packed [u2_w; sc_w] bf16 (16384 elems, B-frag order)
#define WS_PACKB  6400000
#define WS_PACKW2 (WS_PACKB + 131072)

#define NB_U1 3125            // (NPTS*8+255)/256
#define NB_PACK 256
#define NB_PACKW2 64

__device__ __forceinline__ float lrelu(float x) { return x > 0.f ? x : 0.1f * x; }

// exact RNE (used in one-time prep only)
__device__ __forceinline__ u32 f2bf(float f) {
    union { float f; u32 u; } v; v.f = f;
    return (v.u + 0x7FFFu + ((v.u >> 16) & 1u)) >> 16;
}
// fast round-half-up, scalar
__device__ __forceinline__ u16 f2bfF(float f) {
    union { float f; u32 u; } v; v.f = f;
    return (u16)((v.u + 0x8000u) >> 16);
}
// fast round-half-up, packed pair: low u16 = a, high u16 = b
__device__ __forceinline__ u32 pkbf(float a, float b) {
    union { float f; u32 u; } x, y; x.f = a; y.f = b;
    return __builtin_amdgcn_perm(y.u + 0x8000u, x.u + 0x8000u, 0x07060302u);
}

// ---- merged prep: u1 feats + pack lin_w + pack W2 ----
__global__ __launch_bounds__(256) void k_prep(
    const float* __restrict__ df, const float* __restrict__ u1_w,
    const float* __restrict__ u1_b, u16* __restrict__ feats,
    const float* __restrict__ lin_w, u16* __restrict__ packB,
    const float* __restrict__ u2_w, const float* __restrict__ sc_w,
    u16* __restrict__ packW2)
{
    int bid = blockIdx.x;
    if (bid < NB_U1) {
        int t = bid * 256 + threadIdx.x;
        int n = t >> 3, g = t & 7;
        if (n >= NPTS) return;
        int c = g * 4;
        float4 acc = *(const float4*)(u1_b + c);
        const float* row = df + (size_t)n * CIN;
        #pragma unroll
        for (int j = 0; j < CIN; j += 4) {
            float4 f = *(const float4*)(row + j);
            float4 w0 = *(const float4*)(u1_w + (j + 0) * CMID + c);
            float4 w1 = *(const float4*)(u1_w + (j + 1) * CMID + c);
            float4 w2 = *(const float4*)(u1_w + (j + 2) * CMID + c);
            float4 w3 = *(const float4*)(u1_w + (j + 3) * CMID + c);
            acc.x += f.x * w0.x + f.y * w1.x + f.z * w2.x + f.w * w3.x;
            acc.y += f.x * w0.y + f.y * w1.y + f.z * w2.y + f.w * w3.y;
            acc.z += f.x * w0.z + f.y * w1.z + f.z * w2.z + f.w * w3.z;
            acc.w += f.x * w0.w + f.y * w1.w + f.z * w2.w + f.w * w3.w;
        }
        uint2 o;
        o.x = f2bf(acc.x) | (f2bf(acc.y) << 16);
        o.y = f2bf(acc.z) | (f2bf(acc.w) << 16);
        *(uint2*)(feats + (size_t)n * CMID + c) = o;
    } else if (bid < NB_U1 + NB_PACK) {
        int t = (bid - NB_U1) * 256 + threadIdx.x;     // 65536 total
        int j = t & 7, ln = (t >> 3) & 63, s = t >> 9;
        int nt = s & 3, kb = s >> 2;
        int k = kb * 32 + (ln >> 4) * 8 + j;
        int n = nt * 16 + (ln & 15);
        packB[t] = (u16)f2bf(lin_w[k * 64 + n]);
    } else {
        int t = (bid - NB_U1 - NB_PACK) * 256 + threadIdx.x;   // 16384 total
        int j = t & 7, ln = (t >> 3) & 63, s = t >> 9;
        int nt2 = s & 7, kb2 = s >> 3;
        int k = kb2 * 32 + (ln >> 4) * 8 + j;
        int n = nt2 * 16 + (ln & 15);
        float v = (k < 64) ? u2_w[k * COUT + n] : sc_w[(k - 64) * COUT + n];
        packW2[t] = (u16)f2bf(v);
    }
}

// ---- Fused: gather/PE/WN/einsum (phase 1) + GEMM1 + GEMM2 (phase 2). ----
// Block = 256 threads = 16 points; one wave handles 4 points in phase 1.
__global__ __launch_bounds__(256) void k_fused(
    const float* __restrict__ xyz, const int* __restrict__ nei,
    const u16* __restrict__ feats,
    const float* __restrict__ pe_w1, const float* __restrict__ pe_b1,
    const float* __restrict__ pe_w2, const float* __restrict__ pe_b2,
    const float* __restrict__ wn_w1, const float* __restrict__ wn_b1,
    const float* __restrict__ wn_w2, const float* __restrict__ wn_b2,
    const float* __restrict__ wn_w3, const float* __restrict__ wn_b3,
    const u16* __restrict__ packB, const u16* __restrict__ packW2,
    const float* __restrict__ lin_b,
    const float* __restrict__ u2_b, const float* __restrict__ sc_b,
    const float* __restrict__ df, float* __restrict__ out,
    float* __restrict__ locout)
{
    __shared__ __align__(16) u16 aggL[16 * APITCH];   // 33,024 B, no swizzle
    __shared__ float loc_s[4][4][16][3];              //  3,072 B (wave-private)
    __shared__ int   idx_s[4][4][16];                 //  1,024 B (wave-private)
    __shared__ __align__(16) u16 pexd[4][32][24];     //  6,144 B; pe_s in ph1, xd in ph2
    __shared__ __align__(16) u16 w_s[4][16][24];      //  3,072 B (wave-private)

    u16* xd = &pexd[0][0][0];                         // phase-2 alias (4 KB used)

    const int tid = threadIdx.x, wv = tid >> 6, lane = tid & 63;
    const int quad = lane >> 4, nl = lane & 15;
    const int p0 = blockIdx.x * 16;
    const int ptBase = p0 + wv * 4;

    // ---- phase 1, step 0: coords + indices (lane: point=quad, k=nl) ----
    int pt0 = ptBase + quad;
    int idx0 = nei[pt0 * KNEI + nl];
    idx_s[wv][quad][nl] = idx0;
    {
        float cx = xyz[pt0 * 3 + 0], cy = xyz[pt0 * 3 + 1], cz = xyz[pt0 * 3 + 2];
        float lx = xyz[idx0 * 3 + 0] - cx;
        float ly = xyz[idx0 * 3 + 1] - cy;
        float lz = xyz[idx0 * 3 + 2] - cz;
        loc_s[wv][quad][nl][0] = lx;
        loc_s[wv][quad][nl][1] = ly;
        loc_s[wv][quad][nl][2] = lz;
        float* lo = locout + (size_t)(pt0 * KNEI + nl) * 3;
        lo[0] = lx; lo[1] = ly; lo[2] = lz;
    }

    // ---- preload per-lane weights ----
    float w1r0[8], w1r1[8], w1r2[8], b1v[8];
    #pragma unroll
    for (int j = 0; j < 8; ++j) {
        int h = quad * 8 + j;
        w1r0[j] = pe_w1[h]; w1r1[j] = pe_w1[32 + h]; w1r2[j] = pe_w1[64 + h];
        b1v[j] = pe_b1[h];
    }
    bf16x8 w2t[2];
    #pragma unroll
    for (int ct = 0; ct < 2; ++ct)
        #pragma unroll
        for (int j = 0; j < 8; ++j)
            w2t[ct][j] = (short)f2bf(pe_w2[(quad * 8 + j) * 32 + nl + 16 * ct]);
    float b2v[2][4];
    #pragma unroll
    for (int ct = 0; ct < 2; ++ct)
        #pragma unroll
        for (int r = 0; r < 4; ++r)
            b2v[ct][r] = pe_b2[16 * ct + quad * 4 + r];
    float wn3v[8][4], wnb3v[4];
    #pragma unroll
    for (int h = 0; h < 8; ++h)
        #pragma unroll
        for (int r = 0; r < 4; ++r)
            wn3v[h][r] = wn_w3[h * 16 + quad * 4 + r];
    #pragma unroll
    for (int r = 0; r < 4; ++r) wnb3v[r] = wn_b3[quad * 4 + r];

    const f32x4 zacc = {0.f, 0.f, 0.f, 0.f};

    for (int p = 0; p < 4; ++p) {
        const int m = wv * 4 + p;   // block-local point row

        // ---- feats gather straight into B-frag (quads 0,1; 2,3 zero) ----
        bf16x8 featf0 = 0, featf1 = 0;
        if (quad < 2) {
            #pragma unroll
            for (int j = 0; j < 8; ++j) {
                int idk = idx_s[wv][p][quad * 8 + j];
                featf0[j] = (short)feats[(size_t)idk * CMID + nl];
                featf1[j] = (short)feats[(size_t)idk * CMID + nl + 16];
            }
        }

        float lx = loc_s[wv][p][nl][0];
        float ly = loc_s[wv][p][nl][1];
        float lz = loc_s[wv][p][nl][2];

        // ---- B1: ph in B-frag layout (h=quad*8+j, k_nei=nl) ----
        bf16x8 phf;
        {
            u32* ph32 = (u32*)&phf;
            #pragma unroll
            for (int j = 0; j < 8; j += 2) {
                float v0 = lrelu(b1v[j]     + lx * w1r0[j]     + ly * w1r1[j]     + lz * w1r2[j]);
                float v1 = lrelu(b1v[j + 1] + lx * w1r0[j + 1] + ly * w1r1[j + 1] + lz * w1r2[j + 1]);
                ph32[j >> 1] = pkbf(v0, v1);
            }
        }

        // ---- B2: pe^T = w2^T @ ph : 2 MFMAs ----
        f32x4 pe0 = __builtin_amdgcn_mfma_f32_16x16x32_bf16(w2t[0], phf, zacc, 0, 0, 0);
        f32x4 pe1 = __builtin_amdgcn_mfma_f32_16x16x32_bf16(w2t[1], phf, zacc, 0, 0, 0);

        #pragma unroll
        for (int r = 0; r < 4; ++r) {
            pexd[wv][quad * 4 + r][nl]      = f2bfF(lrelu(pe0[r] + b2v[0][r]));
            pexd[wv][16 + quad * 4 + r][nl] = f2bfF(lrelu(pe1[r] + b2v[1][r]));
        }

        // ---- WeightNet (k=nl; lane computes o=quad*4+r) ----
        {
            float h1[8], h2[8];
            #pragma unroll
            for (int h = 0; h < 8; ++h)
                h1[h] = lrelu(wn_b1[h] + lx * wn_w1[h] + ly * wn_w1[8 + h] + lz * wn_w1[16 + h]);
            #pragma unroll
            for (int o2 = 0; o2 < 8; ++o2) {
                float a = wn_b2[o2];
                #pragma unroll
                for (int h = 0; h < 8; ++h) a += h1[h] * wn_w2[h * 8 + o2];
                h2[o2] = a;
            }
            #pragma unroll
            for (int r = 0; r < 4; ++r) {
                float a = wnb3v[r];
                #pragma unroll
                for (int h = 0; h < 8; ++h) a += h2[h] * wn3v[h][r];
                w_s[wv][quad * 4 + r][nl] = f2bfF(lrelu(a));
            }
        }
        // wave-private LDS: intra-wave ds_write->ds_read ordering is enforced
        // by the in-order LDS queue + compiler lgkmcnt; no block barrier needed.

        // ---- read frags: wA (A: o=nl, k=quad*8+j), peB (B: k, c=nl) ----
        bf16x8 wA = 0, peB0 = 0, peB1 = 0;
        if (quad < 2) {
            wA   = *(const bf16x8*)&w_s[wv][nl][quad * 8];
            peB0 = *(const bf16x8*)&pexd[wv][nl][quad * 8];
            peB1 = *(const bf16x8*)&pexd[wv][nl + 16][quad * 8];
        }

        // ---- einsum: D[o][c] = w^T @ nf, 4 c-tiles, K=16 (padded) ----
        f32x4 c0a = __builtin_amdgcn_mfma_f32_16x16x32_bf16(wA, featf0, zacc, 0, 0, 0);
        f32x4 c1a = __builtin_amdgcn_mfma_f32_16x16x32_bf16(wA, featf1, zacc, 0, 0, 0);
        f32x4 c2a = __builtin_amdgcn_mfma_f32_16x16x32_bf16(wA, peB0, zacc, 0, 0, 0);
        f32x4 c3a = __builtin_amdgcn_mfma_f32_16x16x32_bf16(wA, peB1, zacc, 0, 0, 0);

        // ---- store agg row into LDS (plain layout, pitch 1032) ----
        {
            u16* arow = aggL + m * APITCH;
            f32x4 cc[4] = {c0a, c1a, c2a, c3a};
            #pragma unroll
            for (int ct = 0; ct < 4; ++ct) {
                int e = (nl + 16 * ct) * 16 + quad * 4;
                uint2 o;
                o.x = pkbf(cc[ct][0], cc[ct][1]);
                o.y = pkbf(cc[ct][2], cc[ct][3]);
                *(uint2*)(arow + e) = o;
            }
        }
    }
    __syncthreads();   // all aggL rows visible; pe_s region now dead -> xd

    // ================= phase 2 =================
    // GEMM1: x[16][64] = lrelu(agg @ lin_w + lin_b); wave wv owns n-tile nt=wv.
    const int nt = wv;
    {
        const u16* bp = packB + nt * 512 + lane * 8;
        const u16* arow = aggL + nl * APITCH;
        f32x4 accA = zacc, accB = zacc;
        #pragma unroll
        for (int kk = 0; kk < 16; ++kk) {
            int kbA = 2 * kk, kbB = 2 * kk + 1;
            bf16x8 aA = *(const bf16x8*)(arow + (4 * kbA + quad) * 8);
            bf16x8 aB = *(const bf16x8*)(arow + (4 * kbB + quad) * 8);
            bf16x8 bA = *(const bf16x8*)(bp + kbA * 2048);
            bf16x8 bB = *(const bf16x8*)(bp + kbB * 2048);
            accA = __builtin_amdgcn_mfma_f32_16x16x32_bf16(aA, bA, accA, 0, 0, 0);
            accB = __builtin_amdgcn_mfma_f32_16x16x32_bf16(aB, bB, accB, 0, 0, 0);
        }
        // epilogue: lane holds x[m=quad*4+r][col=nt*16+nl] -> xd A-frag
        int col = nt * 16 + nl;
        float lb = lin_b[col];
        int kb2 = col >> 5, q2 = (col >> 3) & 3, j2 = col & 7;
        #pragma unroll
        for (int r = 0; r < 4; ++r) {
            int m = quad * 4 + r;
            float v = lrelu(accA[r] + accB[r] + lb);
            xd[(kb2 * 64 + q2 * 16 + m) * 8 + j2] = f2bfF(v);
        }
    }
    // df -> xd (cols 64..127)
    if (tid < 128) {
        int m = tid >> 3, cg = tid & 7;
        int colk = 64 + cg * 8;
        const float* dfr = df + (size_t)(p0 + m) * CIN + cg * 8;
        float4 f0 = *(const float4*)(dfr);
        float4 f1 = *(const float4*)(dfr + 4);
        int kb2 = colk >> 5, q2 = (colk >> 3) & 3;
        uint4 o;
        o.x = pkbf(f0.x, f0.y);
        o.y = pkbf(f0.z, f0.w);
        o.z = pkbf(f1.x, f1.y);
        o.w = pkbf(f1.z, f1.w);
        *(uint4*)(xd + (kb2 * 64 + q2 * 16 + m) * 8) = o;
    }
    __syncthreads();

    // GEMM2: out[16][128] = lrelu([x|df] @ W2 + u2_b + sc_b); wave owns 2 n-tiles
    {
        f32x4 acc20 = zacc, acc21 = zacc;
        #pragma unroll
        for (int kb = 0; kb < 4; ++kb) {
            bf16x8 a = *(const bf16x8*)(xd + (kb * 64 + lane) * 8);
            bf16x8 b0 = *(const bf16x8*)(packW2 + (size_t)(kb * 8 + wv * 2 + 0) * 512 + lane * 8);
            bf16x8 b1 = *(const bf16x8*)(packW2 + (size_t)(kb * 8 + wv * 2 + 1) * 512 + lane * 8);
            acc20 = __builtin_amdgcn_mfma_f32_16x16x32_bf16(a, b0, acc20, 0, 0, 0);
            acc21 = __builtin_amdgcn_mfma_f32_16x16x32_bf16(a, b1, acc21, 0, 0, 0);
        }
        #pragma unroll
        for (int t = 0; t < 2; ++t) {
            f32x4 ac = t ? acc21 : acc20;
            int colo = (wv * 2 + t) * 16 + nl;
            float bias = u2_b[colo] + sc_b[colo];
            #pragma unroll
            for (int r = 0; r < 4; ++r) {
                int m = quad * 4 + r;
                out[(size_t)(p0 + m) * COUT + colo] = lrelu(ac[r] + bias);
            }
        }
    }
}

extern "C" void kernel_launch(void* const* d_in, const int* in_sizes, int n_in,
                              void* d_out, int out_size, void* d_ws, size_t ws_size,
                              hipStream_t stream) {
    const float* xyz   = (const float*)d_in[0];
    const float* df    = (const float*)d_in[1];
    const int*   nei   = (const int*)d_in[2];
    const float* pe_w1 = (const float*)d_in[3];
    const float* pe_b1 = (const float*)d_in[4];
    const float* pe_w2 = (const float*)d_in[5];
    const float* pe_b2 = (const float*)d_in[6];
    const float* u1_w  = (const float*)d_in[7];
    const float* u1_b  = (const float*)d_in[8];
    const float* wn_w1 = (const float*)d_in[9];
    const float* wn_b1 = (const float*)d_in[10];
    const float* wn_w2 = (const float*)d_in[11];
    const float* wn_b2 = (const float*)d_in[12];
    const float* wn_w3 = (const float*)d_in[13];
    const float* wn_b3 = (const float*)d_in[14];
    const float* lin_w = (const float*)d_in[15];
    const float* lin_b = (const float*)d_in[16];
    const float* u2_w  = (const float*)d_in[17];
    const float* u2_b  = (const float*)d_in[18];
    const float* sc_w  = (const float*)d_in[19];
    const float* sc_b  = (const float*)d_in[20];

    u16* feats  = (u16*)d_ws;
    u16* packB  = (u16*)((char*)d_ws + WS_PACKB);
    u16* packW2 = (u16*)((char*)d_ws + WS_PACKW2);
    float* outp = (float*)d_out;
    float* locout = outp + (size_t)NPTS * COUT;

    hipLaunchKernelGGL(k_prep, dim3(NB_U1 + NB_PACK + NB_PACKW2), dim3(256), 0, stream,
                       df, u1_w, u1_b, feats, lin_w, packB, u2_w, sc_w, packW2);

    hipLaunchKernelGGL(k_fused, dim3(NPTS / 16), dim3(256), 0, stream,
                       xyz, nei, feats,
                       pe_w1, pe_b1, pe_w2, pe_b2,
                       wn_w1, wn_b1, wn_w2, wn_b2, wn_w3, wn_b3,
                       packB, packW2, lin_b, u2_b, sc_b,
                       df, outp, locout);
}

// Round 8
// 251.556 us; speedup vs baseline: 7.4293x; 1.1700x over previous
//
#include <hip/hip_runtime.h>
#include <stdint.h>

#define NPTS 100000
#define KNEI 16
#define CIN 64
#define CMID 32
#define CONC 64
#define LINI 1024
#define COUT 128
#define APITCH 1032   // u16 per aggL row (keeps b128 16B alignment; spread verified)

typedef unsigned short u16;
typedef unsigned int u32;
typedef __attribute__((ext_vector_type(8))) short bf16x8;
typedef __attribute__((ext_vector_type(4))) float f32x4;

// ws layout (bytes):
//   [0, 6400000)            feats2: u32[N][16], channel-paired (c | c+16<<16)
//   [WS_PACKB, +131072)     packed lin_w bf16 (65536 elems, MFMA B-frag order)
//   [WS_PACKW2, +32768)     packed [u2_w; sc_w] bf16 (16384 elems, B-frag order)
//   [WS_WN, +576)           folded WeightNet: W23[8][16] fp32, b23[16] fp32
#define WS_PACKB  6400000
#define WS_PACKW2 (WS_PACKB + 131072)
#define WS_WN     (WS_PACKW2 + 32768)

#define NB_U1 1563            // (NPTS*4+255)/256
#define NB_PACK 256
#define NB_PACKW2 64

__device__ __forceinline__ float lrelu(float x) { return x > 0.f ? x : 0.1f * x; }

// exact RNE (one-time prep only)
__device__ __forceinline__ u32 f2bf(float f) {
    union { float f; u32 u; } v; v.f = f;
    return (v.u + 0x7FFFu + ((v.u >> 16) & 1u)) >> 16;
}
// fast round-half-up, scalar
__device__ __forceinline__ u16 f2bfF(float f) {
    union { float f; u32 u; } v; v.f = f;
    return (u16)((v.u + 0x8000u) >> 16);
}
// fast round-half-up, packed pair (low=a, high=b)
__device__ __forceinline__ u32 pkbf(float a, float b) {
    union { float f; u32 u; } x, y; x.f = a; y.f = b;
    return __builtin_amdgcn_perm(y.u + 0x8000u, x.u + 0x8000u, 0x07060302u);
}
__device__ __forceinline__ float bf2f(u32 h) {
    union { u32 u; float f; } v; v.u = h << 16; return v.f;
}

// ---- merged prep: u1 feats (paired) + pack lin_w + pack W2 + fold WeightNet ----
__global__ __launch_bounds__(256) void k_prep(
    const float* __restrict__ df, const float* __restrict__ u1_w,
    const float* __restrict__ u1_b, u32* __restrict__ feats2,
    const float* __restrict__ lin_w, u16* __restrict__ packB,
    const float* __restrict__ u2_w, const float* __restrict__ sc_w,
    u16* __restrict__ packW2,
    const float* __restrict__ wn_w2, const float* __restrict__ wn_b2,
    const float* __restrict__ wn_w3, const float* __restrict__ wn_b3,
    float* __restrict__ wnf)
{
    int bid = blockIdx.x;
    if (bid < NB_U1) {
        int t = bid * 256 + threadIdx.x;
        int n = t >> 2, g = t & 3;
        if (n >= NPTS) return;
        int c = g * 4;
        float4 alo = *(const float4*)(u1_b + c);
        float4 ahi = *(const float4*)(u1_b + c + 16);
        const float* row = df + (size_t)n * CIN;
        #pragma unroll
        for (int j = 0; j < CIN; j += 4) {
            float4 f = *(const float4*)(row + j);
            #pragma unroll
            for (int s = 0; s < 4; ++s) {
                float fv = s == 0 ? f.x : s == 1 ? f.y : s == 2 ? f.z : f.w;
                float4 wl = *(const float4*)(u1_w + (j + s) * CMID + c);
                float4 wh = *(const float4*)(u1_w + (j + s) * CMID + c + 16);
                alo.x += fv * wl.x; alo.y += fv * wl.y; alo.z += fv * wl.z; alo.w += fv * wl.w;
                ahi.x += fv * wh.x; ahi.y += fv * wh.y; ahi.z += fv * wh.z; ahi.w += fv * wh.w;
            }
        }
        uint4 o;
        o.x = f2bf(alo.x) | (f2bf(ahi.x) << 16);
        o.y = f2bf(alo.y) | (f2bf(ahi.y) << 16);
        o.z = f2bf(alo.z) | (f2bf(ahi.z) << 16);
        o.w = f2bf(alo.w) | (f2bf(ahi.w) << 16);
        *(uint4*)(feats2 + (size_t)n * 16 + c) = o;
    } else if (bid < NB_U1 + NB_PACK) {
        int t = (bid - NB_U1) * 256 + threadIdx.x;     // 65536 total
        int j = t & 7, ln = (t >> 3) & 63, s = t >> 9;
        int nt = s & 3, kb = s >> 2;
        int k = kb * 32 + (ln >> 4) * 8 + j;
        int n = nt * 16 + (ln & 15);
        packB[t] = (u16)f2bf(lin_w[k * 64 + n]);
    } else if (bid < NB_U1 + NB_PACK + NB_PACKW2) {
        int t = (bid - NB_U1 - NB_PACK) * 256 + threadIdx.x;   // 16384 total
        int j = t & 7, ln = (t >> 3) & 63, s = t >> 9;
        int nt2 = s & 7, kb2 = s >> 3;
        int k = kb2 * 32 + (ln >> 4) * 8 + j;
        int n = nt2 * 16 + (ln & 15);
        float v = (k < 64) ? u2_w[k * COUT + n] : sc_w[(k - 64) * COUT + n];
        packW2[t] = (u16)f2bf(v);
    } else {
        int t = threadIdx.x;
        if (t < 128) {
            int i = t >> 4, o = t & 15;
            float a = 0.f;
            #pragma unroll
            for (int m = 0; m < 8; ++m) a += wn_w2[i * 8 + m] * wn_w3[m * 16 + o];
            wnf[i * 16 + o] = a;
        } else if (t < 144) {
            int o = t - 128;
            float a = wn_b3[o];
            #pragma unroll
            for (int m = 0; m < 8; ++m) a += wn_b2[m] * wn_w3[m * 16 + o];
            wnf[128 + o] = a;
        }
    }
}

// ---- Fused: gather/PE/WN/einsum (phase 1) + GEMM1 + GEMM2 (phase 2). ----
// Block = 256 threads = 16 points; one wave handles 4 points in phase 1.
__global__ __launch_bounds__(256) void k_fused(
    const float* __restrict__ xyz, const int* __restrict__ nei,
    const u32* __restrict__ feats2,
    const float* __restrict__ pe_w1, const float* __restrict__ pe_b1,
    const float* __restrict__ pe_w2, const float* __restrict__ pe_b2,
    const float* __restrict__ wn_w1, const float* __restrict__ wn_b1,
    const float* __restrict__ wnf,
    const u16* __restrict__ packB, const u16* __restrict__ packW2,
    const float* __restrict__ lin_b,
    const float* __restrict__ u2_b, const float* __restrict__ sc_b,
    const float* __restrict__ df, float* __restrict__ out,
    float* __restrict__ locout)
{
    __shared__ __align__(16) u16 aggL[16 * APITCH];   // 33,024 B
    __shared__ float loc_s[4][4][16][3];              //  3,072 B (wave-private)
    __shared__ int   idx_s[4][4][16];                 //  1,024 B (wave-private)
    __shared__ __align__(16) u16 pexd[4][32][24];     //  6,144 B; pe in ph1, xd in ph2
    __shared__ __align__(16) u16 w_s[4][16][24];      //  3,072 B (wave-private)
    __shared__ __align__(16) u16 h1_s[4][4][16][8];   //  4,096 B bf16 h1 per (p,k)

    u16* xd = &pexd[0][0][0];                         // phase-2 alias (4 KB used)

    const int tid = threadIdx.x, wv = tid >> 6, lane = tid & 63;
    const int quad = lane >> 4, nl = lane & 15;
    const int p0 = blockIdx.x * 16;
    const int ptBase = p0 + wv * 4;

    // ---- phase 1, step 0: coords + indices + deduped h1 (lane: point=quad, k=nl) ----
    int pt0 = ptBase + quad;
    int idx0 = nei[pt0 * KNEI + nl];
    idx_s[wv][quad][nl] = idx0;
    {
        float cx = xyz[pt0 * 3 + 0], cy = xyz[pt0 * 3 + 1], cz = xyz[pt0 * 3 + 2];
        float lx0 = xyz[idx0 * 3 + 0] - cx;
        float ly0 = xyz[idx0 * 3 + 1] - cy;
        float lz0 = xyz[idx0 * 3 + 2] - cz;
        loc_s[wv][quad][nl][0] = lx0;
        loc_s[wv][quad][nl][1] = ly0;
        loc_s[wv][quad][nl][2] = lz0;
        float* lo = locout + (size_t)(pt0 * KNEI + nl) * 3;
        lo[0] = lx0; lo[1] = ly0; lo[2] = lz0;
        // WeightNet layer-1 (only nonlinearity before the fold), bf16-packed
        uint4 hp;
        u32* hpp = (u32*)&hp;
        #pragma unroll
        for (int h = 0; h < 8; h += 2) {
            float a = lrelu(wn_b1[h]     + lx0 * wn_w1[h]     + ly0 * wn_w1[8 + h]     + lz0 * wn_w1[16 + h]);
            float b = lrelu(wn_b1[h + 1] + lx0 * wn_w1[h + 1] + ly0 * wn_w1[8 + h + 1] + lz0 * wn_w1[16 + h + 1]);
            hpp[h >> 1] = pkbf(a, b);
        }
        *(uint4*)&h1_s[wv][quad][nl][0] = hp;
    }

    // ---- preload per-lane weights ----
    float w1r0[8], w1r1[8], w1r2[8], b1v[8];
    #pragma unroll
    for (int j = 0; j < 8; ++j) {
        int h = quad * 8 + j;
        w1r0[j] = pe_w1[h]; w1r1[j] = pe_w1[32 + h]; w1r2[j] = pe_w1[64 + h];
        b1v[j] = pe_b1[h];
    }
    bf16x8 w2t[2];
    #pragma unroll
    for (int ct = 0; ct < 2; ++ct)
        #pragma unroll
        for (int j = 0; j < 8; ++j)
            w2t[ct][j] = (short)f2bf(pe_w2[(quad * 8 + j) * 32 + nl + 16 * ct]);
    float b2v[2][4];
    #pragma unroll
    for (int ct = 0; ct < 2; ++ct)
        #pragma unroll
        for (int r = 0; r < 4; ++r)
            b2v[ct][r] = pe_b2[16 * ct + quad * 4 + r];
    float wn3v[8][4], b23v[4];
    #pragma unroll
    for (int h = 0; h < 8; ++h)
        #pragma unroll
        for (int r = 0; r < 4; ++r)
            wn3v[h][r] = wnf[h * 16 + quad * 4 + r];
    #pragma unroll
    for (int r = 0; r < 4; ++r) b23v[r] = wnf[128 + quad * 4 + r];

    const f32x4 zacc = {0.f, 0.f, 0.f, 0.f};

    for (int p = 0; p < 4; ++p) {
        const int m = wv * 4 + p;   // block-local point row

        // ---- paired feats gather into B-frags (quads 0,1; 2,3 zero) ----
        bf16x8 featf0 = 0, featf1 = 0;
        if (quad < 2) {
            #pragma unroll
            for (int j = 0; j < 8; ++j) {
                int idk = idx_s[wv][p][quad * 8 + j];
                u32 v = feats2[(size_t)idk * 16 + nl];
                featf0[j] = (short)(v & 0xffffu);
                featf1[j] = (short)(v >> 16);
            }
        }

        float lx = loc_s[wv][p][nl][0];
        float ly = loc_s[wv][p][nl][1];
        float lz = loc_s[wv][p][nl][2];

        // ---- B1: ph in B-frag layout (h=quad*8+j, k_nei=nl) ----
        bf16x8 phf;
        {
            u32* ph32 = (u32*)&phf;
            #pragma unroll
            for (int j = 0; j < 8; j += 2) {
                float v0 = lrelu(b1v[j]     + lx * w1r0[j]     + ly * w1r1[j]     + lz * w1r2[j]);
                float v1 = lrelu(b1v[j + 1] + lx * w1r0[j + 1] + ly * w1r1[j + 1] + lz * w1r2[j + 1]);
                ph32[j >> 1] = pkbf(v0, v1);
            }
        }

        // ---- B2: pe^T = w2^T @ ph : 2 MFMAs ----
        f32x4 pe0 = __builtin_amdgcn_mfma_f32_16x16x32_bf16(w2t[0], phf, zacc, 0, 0, 0);
        f32x4 pe1 = __builtin_amdgcn_mfma_f32_16x16x32_bf16(w2t[1], phf, zacc, 0, 0, 0);

        #pragma unroll
        for (int r = 0; r < 4; ++r) {
            pexd[wv][quad * 4 + r][nl]      = f2bfF(lrelu(pe0[r] + b2v[0][r]));
            pexd[wv][16 + quad * 4 + r][nl] = f2bfF(lrelu(pe1[r] + b2v[1][r]));
        }

        // ---- folded WeightNet output (h1 from LDS broadcast, W23 in regs) ----
        {
            uint4 hv = *(const uint4*)&h1_s[wv][p][nl][0];
            float h1f[8];
            h1f[0] = bf2f(hv.x & 0xffffu); h1f[1] = bf2f(hv.x >> 16);
            h1f[2] = bf2f(hv.y & 0xffffu); h1f[3] = bf2f(hv.y >> 16);
            h1f[4] = bf2f(hv.z & 0xffffu); h1f[5] = bf2f(hv.z >> 16);
            h1f[6] = bf2f(hv.w & 0xffffu); h1f[7] = bf2f(hv.w >> 16);
            #pragma unroll
            for (int r = 0; r < 4; ++r) {
                float a = b23v[r];
                #pragma unroll
                for (int h = 0; h < 8; ++h) a += h1f[h] * wn3v[h][r];
                w_s[wv][quad * 4 + r][nl] = f2bfF(lrelu(a));
            }
        }
        // wave-private LDS: intra-wave ordering via lgkmcnt; no block barrier.

        // ---- read frags: wA (A: o=nl, k=quad*8+j), peB (B: k, c=nl) ----
        bf16x8 wA = 0, peB0 = 0, peB1 = 0;
        if (quad < 2) {
            wA   = *(const bf16x8*)&w_s[wv][nl][quad * 8];
            peB0 = *(const bf16x8*)&pexd[wv][nl][quad * 8];
            peB1 = *(const bf16x8*)&pexd[wv][nl + 16][quad * 8];
        }

        // ---- einsum: D[o][c] = w^T @ nf, 4 c-tiles, K=16 (padded) ----
        f32x4 c0a = __builtin_amdgcn_mfma_f32_16x16x32_bf16(wA, featf0, zacc, 0, 0, 0);
        f32x4 c1a = __builtin_amdgcn_mfma_f32_16x16x32_bf16(wA, featf1, zacc, 0, 0, 0);
        f32x4 c2a = __builtin_amdgcn_mfma_f32_16x16x32_bf16(wA, peB0, zacc, 0, 0, 0);
        f32x4 c3a = __builtin_amdgcn_mfma_f32_16x16x32_bf16(wA, peB1, zacc, 0, 0, 0);

        // ---- store agg row into LDS (plain layout, pitch 1032) ----
        {
            u16* arow = aggL + m * APITCH;
            f32x4 cc[4] = {c0a, c1a, c2a, c3a};
            #pragma unroll
            for (int ct = 0; ct < 4; ++ct) {
                int e = (nl + 16 * ct) * 16 + quad * 4;
                uint2 o;
                o.x = pkbf(cc[ct][0], cc[ct][1]);
                o.y = pkbf(cc[ct][2], cc[ct][3]);
                *(uint2*)(arow + e) = o;
            }
        }
    }
    __syncthreads();   // all aggL rows visible; pe region now dead -> xd

    // ================= phase 2 =================
    // GEMM1: x[16][64] = lrelu(agg @ lin_w + lin_b); wave wv owns n-tile nt=wv.
    const int nt = wv;
    {
        const u16* bp = packB + nt * 512 + lane * 8;
        const u16* arow = aggL + nl * APITCH;
        f32x4 accA = zacc, accB = zacc;
        #pragma unroll
        for (int kk = 0; kk < 16; ++kk) {
            int kbA = 2 * kk, kbB = 2 * kk + 1;
            bf16x8 aA = *(const bf16x8*)(arow + (4 * kbA + quad) * 8);
            bf16x8 aB = *(const bf16x8*)(arow + (4 * kbB + quad) * 8);
            bf16x8 bA = *(const bf16x8*)(bp + kbA * 2048);
            bf16x8 bB = *(const bf16x8*)(bp + kbB * 2048);
            accA = __builtin_amdgcn_mfma_f32_16x16x32_bf16(aA, bA, accA, 0, 0, 0);
            accB = __builtin_amdgcn_mfma_f32_16x16x32_bf16(aB, bB, accB, 0, 0, 0);
        }
        int col = nt * 16 + nl;
        float lb = lin_b[col];
        int kb2 = col >> 5, q2 = (col >> 3) & 3, j2 = col & 7;
        #pragma unroll
        for (int r = 0; r < 4; ++r) {
            int mm = quad * 4 + r;
            float v = lrelu(accA[r] + accB[r] + lb);
            xd[(kb2 * 64 + q2 * 16 + mm) * 8 + j2] = f2bfF(v);
        }
    }
    // df -> xd (cols 64..127)
    if (tid < 128) {
        int mm = tid >> 3, cg = tid & 7;
        int colk = 64 + cg * 8;
        const float* dfr = df + (size_t)(p0 + mm) * CIN + cg * 8;
        float4 f0 = *(const float4*)(dfr);
        float4 f1 = *(const float4*)(dfr + 4);
        int kb2 = colk >> 5, q2 = (colk >> 3) & 3;
        uint4 o;
        o.x = pkbf(f0.x, f0.y);
        o.y = pkbf(f0.z, f0.w);
        o.z = pkbf(f1.x, f1.y);
        o.w = pkbf(f1.z, f1.w);
        *(uint4*)(xd + (kb2 * 64 + q2 * 16 + mm) * 8) = o;
    }
    __syncthreads();

    // GEMM2: out[16][128] = lrelu([x|df] @ W2 + u2_b + sc_b); wave owns 2 n-tiles
    {
        f32x4 acc20 = zacc, acc21 = zacc;
        #pragma unroll
        for (int kb = 0; kb < 4; ++kb) {
            bf16x8 a = *(const bf16x8*)(xd + (kb * 64 + lane) * 8);
            bf16x8 b0 = *(const bf16x8*)(packW2 + (size_t)(kb * 8 + wv * 2 + 0) * 512 + lane * 8);
            bf16x8 b1 = *(const bf16x8*)(packW2 + (size_t)(kb * 8 + wv * 2 + 1) * 512 + lane * 8);
            acc20 = __builtin_amdgcn_mfma_f32_16x16x32_bf16(a, b0, acc20, 0, 0, 0);
            acc21 = __builtin_amdgcn_mfma_f32_16x16x32_bf16(a, b1, acc21, 0, 0, 0);
        }
        #pragma unroll
        for (int t = 0; t < 2; ++t) {
            f32x4 ac = t ? acc21 : acc20;
            int colo = (wv * 2 + t) * 16 + nl;
            float bias = u2_b[colo] + sc_b[colo];
            #pragma unroll
            for (int r = 0; r < 4; ++r) {
                int mm = quad * 4 + r;
                out[(size_t)(p0 + mm) * COUT + colo] = lrelu(ac[r] + bias);
            }
        }
    }
}

extern "C" void kernel_launch(void* const* d_in, const int* in_sizes, int n_in,
                              void* d_out, int out_size, void* d_ws, size_t ws_size,
                              hipStream_t stream) {
    const float* xyz   = (const float*)d_in[0];
    const float* df    = (const float*)d_in[1];
    const int*   nei   = (const int*)d_in[2];
    const float* pe_w1 = (const float*)d_in[3];
    const float* pe_b1 = (const float*)d_in[4];
    const float* pe_w2 = (const float*)d_in[5];
    const float* pe_b2 = (const float*)d_in[6];
    const float* u1_w  = (const float*)d_in[7];
    const float* u1_b  = (const float*)d_in[8];
    const float* wn_w1 = (const float*)d_in[9];
    const float* wn_b1 = (const float*)d_in[10];
    const float* wn_w2 = (const float*)d_in[11];
    const float* wn_b2 = (const float*)d_in[12];
    const float* wn_w3 = (const float*)d_in[13];
    const float* wn_b3 = (const float*)d_in[14];
    const float* lin_w = (const float*)d_in[15];
    const float* lin_b = (const float*)d_in[16];
    const float* u2_w  = (const float*)d_in[17];
    const float* u2_b  = (const float*)d_in[18];
    const float* sc_w  = (const float*)d_in[19];
    const float* sc_b  = (const float*)d_in[20];

    u32* feats2 = (u32*)d_ws;
    u16* packB  = (u16*)((char*)d_ws + WS_PACKB);
    u16* packW2 = (u16*)((char*)d_ws + WS_PACKW2);
    float* wnf  = (float*)((char*)d_ws + WS_WN);
    float* outp = (float*)d_out;
    float* locout = outp + (size_t)NPTS * COUT;

    hipLaunchKernelGGL(k_prep, dim3(NB_U1 + NB_PACK + NB_PACKW2 + 1), dim3(256), 0, stream,
                       df, u1_w, u1_b, feats2, lin_w, packB, u2_w, sc_w, packW2,
                       wn_w2, wn_b2, wn_w3, wn_b3, wnf);

    hipLaunchKernelGGL(k_fused, dim3(NPTS / 16), dim3(256), 0, stream,
                       xyz, nei, feats2,
                       pe_w1, pe_b1, pe_w2, pe_b2,
                       wn_w1, wn_b1, wnf,
                       packB, packW2, lin_b, u2_b, sc_b,
                       df, outp, locout);
}